// Round 2
// baseline (183.749 us; speedup 1.0000x reference)
//
#include <hip/hip_runtime.h>
#include <hip/hip_bf16.h>

#define LATENT 4096
#define SDIM   64
#define BK     128
#define NCH    (LATENT / BK)   // 32 K-chunks
#define MT     5               // 5 m-tiles of 16 = 80 rows (64 outputs + s_row + pad)

typedef __bf16 bf16x8 __attribute__((ext_vector_type(8)));
typedef float  f32x4  __attribute__((ext_vector_type(4)));

// Single fused kernel: no workspace, no cross-kernel state.
// D[80 x 16384] = A[80 x 4096](rebuilt per block, LDS) * z^T, fused epilogue.
// block: 512 thr = 8 waves = 4 batch-row-groups x 2 K-halves; 64 batch rows/block.
__global__ __launch_bounds__(512, 2) void fused_kernel(
    const float* __restrict__ z,
    const float* __restrict__ wq, const float* __restrict__ bq,
    const float* __restrict__ wk, const float* __restrict__ bk,
    const float* __restrict__ Wf, const float* __restrict__ bfin,
    const int* __restrict__ midx, int F,
    float* __restrict__ out)
{
    // A double-buffer (2 x 80 x 128 bf16 = 40960 B); reused as redbuf after K loop
    __shared__ __align__(16) unsigned char ubuf[2 * 80 * BK * 2];
    __shared__ int   inv[LATENT];     // 16 KB
    __shared__ float cvals[68];
    __shared__ float srow[4][16];

    __bf16* Ab = (__bf16*)ubuf;
    float (*red)[MT][4][64] = (float (*)[MT][4][64])ubuf;

    const int tid  = threadIdx.x;
    const int lane = tid & 63;
    const int w    = tid >> 6;     // 0..7
    const int rg   = w & 3;        // batch row group
    const int kh   = w >> 2;       // K half within chunk
    const int r0   = blockIdx.x * 64 + rg * 16;
    const int col  = lane & 15;    // batch row within group (MFMA n / D col)
    const int g4   = lane >> 4;

    // ---- phase 0: inverse mask map + bias folds ----
    for (int d = tid; d < LATENT; d += 512) inv[d] = -1;
    __syncthreads();
    for (int f = tid; f < F; f += 512) inv[midx[f]] = f;
    {   // cvals[o] = sum_f bk[f] * Wf[o,f]   (8 lanes per o, xor-reduce)
        const int o = tid >> 3, fo = tid & 7;
        float p = 0.f;
        for (int f = fo; f < F; f += 8) p += bk[f] * Wf[o * F + f];
        p += __shfl_xor(p, 1); p += __shfl_xor(p, 2); p += __shfl_xor(p, 4);
        if (fo == 0) cvals[o] = p;
    }
    if (w == 0) {  // cvals[64] = sum_f bq[f]
        float q = 0.f;
        for (int f = lane; f < F; f += 64) q += bq[f];
        #pragma unroll
        for (int off = 32; off; off >>= 1) q += __shfl_down(q, off);
        if (lane == 0) cvals[64] = q;
    }
    __syncthreads();

    f32x4 acc[MT] = {};

    // build chunk ch of A into buffer b (XOR-swizzled rows, write==read mapping)
    auto build = [&](int ch, int b) {
        const int k  = tid & 127;          // element within chunk (per-lane consecutive)
        const int mb = tid >> 7;           // 0..3 (wave-uniform)
        const int f  = inv[ch * BK + k];
        const float wkf = (f >= 0) ? wk[f] : 0.f;
        const float wqf = (f >= 0) ? wq[f] : 0.f;
        __bf16* dst = Ab + b * 80 * BK;
        #pragma unroll
        for (int i = 0; i < 20; ++i) {
            const int m = mb + 4 * i;      // 0..79
            float x = 0.f;
            if (m < SDIM) { if (f >= 0) x = wkf * Wf[m * F + f]; }
            else if (m == SDIM) x = wqf;
            dst[m * BK + (k ^ ((m & 7) << 3))] = (__bf16)x;
        }
    };

    // one chunk of MFMA work for this wave (its K-half: 2 k-steps of 32)
    auto compute = [&](int ch, int b) {
        const float* zp = z + (size_t)(r0 + col) * LATENT + ch * BK + kh * 64 + g4 * 8;
        f32x4 za0 = *(const f32x4*)(zp);
        f32x4 za1 = *(const f32x4*)(zp + 4);
        f32x4 zb0 = *(const f32x4*)(zp + 32);
        f32x4 zb1 = *(const f32x4*)(zp + 36);
        const __bf16* src = Ab + b * 80 * BK;
        const int kl0 = kh * 64 + g4 * 8;
        bf16x8 bv;
        bv[0] = (__bf16)za0[0]; bv[1] = (__bf16)za0[1];
        bv[2] = (__bf16)za0[2]; bv[3] = (__bf16)za0[3];
        bv[4] = (__bf16)za1[0]; bv[5] = (__bf16)za1[1];
        bv[6] = (__bf16)za1[2]; bv[7] = (__bf16)za1[3];
        #pragma unroll
        for (int mt = 0; mt < MT; ++mt) {
            const int m = mt * 16 + col;
            bf16x8 av = *(const bf16x8*)(src + m * BK + (kl0 ^ ((m & 7) << 3)));
            acc[mt] = __builtin_amdgcn_mfma_f32_16x16x32_bf16(av, bv, acc[mt], 0, 0, 0);
        }
        const int kl1 = kl0 + 32;
        bv[0] = (__bf16)zb0[0]; bv[1] = (__bf16)zb0[1];
        bv[2] = (__bf16)zb0[2]; bv[3] = (__bf16)zb0[3];
        bv[4] = (__bf16)zb1[0]; bv[5] = (__bf16)zb1[1];
        bv[6] = (__bf16)zb1[2]; bv[7] = (__bf16)zb1[3];
        #pragma unroll
        for (int mt = 0; mt < MT; ++mt) {
            const int m = mt * 16 + col;
            bf16x8 av = *(const bf16x8*)(src + m * BK + (kl1 ^ ((m & 7) << 3)));
            acc[mt] = __builtin_amdgcn_mfma_f32_16x16x32_bf16(av, bv, acc[mt], 0, 0, 0);
        }
    };

    // ---- K loop: double-buffered build || compute ----
    build(0, 0);
    __syncthreads();
    #pragma unroll 2
    for (int ch = 0; ch < NCH; ++ch) {
        const int b = ch & 1;
        if (ch + 1 < NCH) build(ch + 1, b ^ 1);
        compute(ch, b);
        __syncthreads();   // build(ch+1) done + A[b] reads done before next overwrite
    }

    // ---- combine K-halves (redbuf reuses A LDS; barrier above protects it) ----
    if (kh == 1) {
        #pragma unroll
        for (int mt = 0; mt < MT; ++mt)
            #pragma unroll
            for (int r = 0; r < 4; ++r) red[rg][mt][r][lane] = acc[mt][r];
    }
    __syncthreads();
    if (kh == 0) {
        #pragma unroll
        for (int mt = 0; mt < MT; ++mt)
            #pragma unroll
            for (int r = 0; r < 4; ++r) acc[mt][r] += red[rg][mt][r][lane];
        if (g4 == 0) srow[rg][col] = acc[4][0];   // m-row 64 = q-row-sum partial
    }
    __syncthreads();

    if (kh == 0) {
        const float s = srow[rg][col] + cvals[64];   // + sum(bias_q)
        const int bidx = r0 + col;
        #pragma unroll
        for (int mt = 0; mt < 4; ++mt) {
            f32x4 cv = *(const f32x4*)(cvals + mt * 16 + g4 * 4);
            f32x4 bf = *(const f32x4*)(bfin + mt * 16 + g4 * 4);
            f32x4 ov;
            #pragma unroll
            for (int r = 0; r < 4; ++r) ov[r] = s * (acc[mt][r] + cv[r]) + bf[r];
            *(f32x4*)(out + (size_t)bidx * SDIM + mt * 16 + g4 * 4) = ov;
        }
    }
}

extern "C" void kernel_launch(void* const* d_in, const int* in_sizes, int n_in,
                              void* d_out, int out_size, void* d_ws, size_t ws_size,
                              hipStream_t stream)
{
    const float* z    = (const float*)d_in[0];
    const float* wq   = (const float*)d_in[1];
    const float* bq   = (const float*)d_in[2];
    const float* wk   = (const float*)d_in[3];
    const float* bk   = (const float*)d_in[4];
    const float* Wf   = (const float*)d_in[5];
    const float* bfin = (const float*)d_in[6];
    const int*   midx = (const int*)d_in[7];
    const int F = in_sizes[1];

    fused_kernel<<<256, 512, 0, stream>>>(z, wq, bq, wk, bk, Wf, bfin, midx, F,
                                          (float*)d_out);
}

// Round 3
// 126.512 us; speedup vs baseline: 1.4524x; 1.4524x over previous
//
#include <hip/hip_runtime.h>
#include <hip/hip_bf16.h>

#define LATENT 4096
#define SDIM   64
#define MT     5              // 5 m-tiles of 16 = 80 rows (64 outputs + s_row + pad)
#define NKS    128            // 4096 / 32 k-steps
#define WS_NEED (32768 + 40960 * 16)

typedef __bf16 bf16x8 __attribute__((ext_vector_type(8)));
typedef float  f32x4  __attribute__((ext_vector_type(4)));

// ======================= precompute path (needs d_ws) =======================

// inv[d] = f if mask_idx[f]==d else -1
__global__ void prep_inv(const int* __restrict__ mask_idx, int F, int* __restrict__ inv) {
    int t = threadIdx.x;
    for (int d = t; d < LATENT; d += 256) inv[d] = -1;
    __syncthreads();
    for (int f = t; f < F; f += 256) inv[mask_idx[f]] = f;
}

// c[o] = sum_f bk[f]*W[o,f] (o<64); c[64] = sum_f bq[f]
__global__ void prep_c(const float* __restrict__ bq, const float* __restrict__ bk,
                       const float* __restrict__ Wf, int F, float* __restrict__ c) {
    int o = blockIdx.x, lane = threadIdx.x;
    float p = 0.f;
    if (o < SDIM) { for (int f = lane; f < F; f += 64) p += bk[f] * Wf[o * F + f]; }
    else          { for (int f = lane; f < F; f += 64) p += bq[f]; }
    for (int off = 32; off; off >>= 1) p += __shfl_down(p, off);
    if (lane == 0) c[o] = p;
}

// bf16 A-fragments, fragment-linear: idx = ((ks*5+mt)*64+lane)
// A[m][k]: m<64 -> wk[f]*W[m,f] at masked k (f=inv[k]); m==64 -> wq[f]; else 0
__global__ void prep_afrag(const float* __restrict__ wq, const float* __restrict__ wk,
                           const float* __restrict__ Wf, const int* __restrict__ inv,
                           int F, bf16x8* __restrict__ afrag) {
    int g = blockIdx.x * 256 + threadIdx.x;      // 0 .. 40959
    int lane = g & 63;
    int mt = (g >> 6) % 5;
    int ks = g / 320;                            // 0 .. 127
    int m = mt * 16 + (lane & 15);
    int kbase = ks * 32 + (lane >> 4) * 8;
    bf16x8 v;
    #pragma unroll
    for (int j = 0; j < 8; ++j) {
        int f = inv[kbase + j];
        float x = 0.f;
        if (f >= 0) {
            if (m < SDIM) x = wk[f] * Wf[m * F + f];
            else if (m == SDIM) x = wq[f];
        }
        v[j] = (__bf16)x;
    }
    afrag[g] = v;
}

// main: D[80 x 16384] = A[80 x 4096] * z^T. No LDS, no barriers.
// 256 thr = 4 waves; each wave: 16 batch rows, full K. 256 blocks.
__global__ __launch_bounds__(256, 4) void gemm_ws(
    const float* __restrict__ z, const bf16x8* __restrict__ afrag,
    const float* __restrict__ c, const float* __restrict__ bfin,
    float* __restrict__ out)
{
    const int tid  = threadIdx.x;
    const int lane = tid & 63;
    const int w    = tid >> 6;     // 0..3
    const int col  = lane & 15;    // batch row within wave (MFMA n / D col)
    const int g4   = lane >> 4;
    const int r0   = blockIdx.x * 64 + w * 16;

    const float*  zp = z + (size_t)(r0 + col) * LATENT + g4 * 8;
    const bf16x8* ap = afrag + lane;

    f32x4 acc[MT] = {};

    f32x4 p0 = *(const f32x4*)(zp);
    f32x4 p1 = *(const f32x4*)(zp + 4);

    #pragma unroll 2
    for (int ks = 0; ks < NKS; ++ks) {
        f32x4 c0 = p0, c1 = p1;
        if (ks + 1 < NKS) {
            p0 = *(const f32x4*)(zp + (ks + 1) * 32);
            p1 = *(const f32x4*)(zp + (ks + 1) * 32 + 4);
        }
        bf16x8 bv;
        bv[0] = (__bf16)c0[0]; bv[1] = (__bf16)c0[1];
        bv[2] = (__bf16)c0[2]; bv[3] = (__bf16)c0[3];
        bv[4] = (__bf16)c1[0]; bv[5] = (__bf16)c1[1];
        bv[6] = (__bf16)c1[2]; bv[7] = (__bf16)c1[3];
        #pragma unroll
        for (int mt = 0; mt < MT; ++mt) {
            bf16x8 av = ap[(ks * MT + mt) * 64];
            acc[mt] = __builtin_amdgcn_mfma_f32_16x16x32_bf16(av, bv, acc[mt], 0, 0, 0);
        }
    }

    // s-row (m=64) lives in acc[4][0] of lanes 0-15; broadcast via shuffle
    const float s = __shfl(acc[4][0], col) + c[SDIM];
    const int b = r0 + col;
    #pragma unroll
    for (int mt = 0; mt < 4; ++mt) {
        f32x4 cv = *(const f32x4*)(c    + mt * 16 + g4 * 4);
        f32x4 bf = *(const f32x4*)(bfin + mt * 16 + g4 * 4);
        f32x4 ov;
        #pragma unroll
        for (int r = 0; r < 4; ++r) ov[r] = s * (acc[mt][r] + cv[r]) + bf[r];
        *(f32x4*)(out + (size_t)b * SDIM + mt * 16 + g4 * 4) = ov;
    }
}

// ================== fused fallback (round-2 kernel, verbatim) ==================
#define BK     128
#define NCH    (LATENT / BK)

__global__ __launch_bounds__(512, 2) void fused_kernel(
    const float* __restrict__ z,
    const float* __restrict__ wq, const float* __restrict__ bq,
    const float* __restrict__ wk, const float* __restrict__ bk,
    const float* __restrict__ Wf, const float* __restrict__ bfin,
    const int* __restrict__ midx, int F,
    float* __restrict__ out)
{
    __shared__ __align__(16) unsigned char ubuf[2 * 80 * BK * 2];
    __shared__ int   inv[LATENT];
    __shared__ float cvals[68];
    __shared__ float srow[4][16];

    __bf16* Ab = (__bf16*)ubuf;
    float (*red)[MT][4][64] = (float (*)[MT][4][64])ubuf;

    const int tid  = threadIdx.x;
    const int lane = tid & 63;
    const int w    = tid >> 6;
    const int rg   = w & 3;
    const int kh   = w >> 2;
    const int r0   = blockIdx.x * 64 + rg * 16;
    const int col  = lane & 15;
    const int g4   = lane >> 4;

    for (int d = tid; d < LATENT; d += 512) inv[d] = -1;
    __syncthreads();
    for (int f = tid; f < F; f += 512) inv[midx[f]] = f;
    {
        const int o = tid >> 3, fo = tid & 7;
        float p = 0.f;
        for (int f = fo; f < F; f += 8) p += bk[f] * Wf[o * F + f];
        p += __shfl_xor(p, 1); p += __shfl_xor(p, 2); p += __shfl_xor(p, 4);
        if (fo == 0) cvals[o] = p;
    }
    if (w == 0) {
        float q = 0.f;
        for (int f = lane; f < F; f += 64) q += bq[f];
        #pragma unroll
        for (int off = 32; off; off >>= 1) q += __shfl_down(q, off);
        if (lane == 0) cvals[64] = q;
    }
    __syncthreads();

    f32x4 acc[MT] = {};

    auto build = [&](int ch, int b) {
        const int k  = tid & 127;
        const int mb = tid >> 7;
        const int f  = inv[ch * BK + k];
        const float wkf = (f >= 0) ? wk[f] : 0.f;
        const float wqf = (f >= 0) ? wq[f] : 0.f;
        __bf16* dst = Ab + b * 80 * BK;
        #pragma unroll
        for (int i = 0; i < 20; ++i) {
            const int m = mb + 4 * i;
            float x = 0.f;
            if (m < SDIM) { if (f >= 0) x = wkf * Wf[m * F + f]; }
            else if (m == SDIM) x = wqf;
            dst[m * BK + (k ^ ((m & 7) << 3))] = (__bf16)x;
        }
    };

    auto compute = [&](int ch, int b) {
        const float* zp = z + (size_t)(r0 + col) * LATENT + ch * BK + kh * 64 + g4 * 8;
        f32x4 za0 = *(const f32x4*)(zp);
        f32x4 za1 = *(const f32x4*)(zp + 4);
        f32x4 zb0 = *(const f32x4*)(zp + 32);
        f32x4 zb1 = *(const f32x4*)(zp + 36);
        const __bf16* src = Ab + b * 80 * BK;
        const int kl0 = kh * 64 + g4 * 8;
        bf16x8 bv;
        bv[0] = (__bf16)za0[0]; bv[1] = (__bf16)za0[1];
        bv[2] = (__bf16)za0[2]; bv[3] = (__bf16)za0[3];
        bv[4] = (__bf16)za1[0]; bv[5] = (__bf16)za1[1];
        bv[6] = (__bf16)za1[2]; bv[7] = (__bf16)za1[3];
        #pragma unroll
        for (int mt = 0; mt < MT; ++mt) {
            const int m = mt * 16 + col;
            bf16x8 av = *(const bf16x8*)(src + m * BK + (kl0 ^ ((m & 7) << 3)));
            acc[mt] = __builtin_amdgcn_mfma_f32_16x16x32_bf16(av, bv, acc[mt], 0, 0, 0);
        }
        const int kl1 = kl0 + 32;
        bv[0] = (__bf16)zb0[0]; bv[1] = (__bf16)zb0[1];
        bv[2] = (__bf16)zb0[2]; bv[3] = (__bf16)zb0[3];
        bv[4] = (__bf16)zb1[0]; bv[5] = (__bf16)zb1[1];
        bv[6] = (__bf16)zb1[2]; bv[7] = (__bf16)zb1[3];
        #pragma unroll
        for (int mt = 0; mt < MT; ++mt) {
            const int m = mt * 16 + col;
            bf16x8 av = *(const bf16x8*)(src + m * BK + (kl1 ^ ((m & 7) << 3)));
            acc[mt] = __builtin_amdgcn_mfma_f32_16x16x32_bf16(av, bv, acc[mt], 0, 0, 0);
        }
    };

    build(0, 0);
    __syncthreads();
    #pragma unroll 2
    for (int ch = 0; ch < NCH; ++ch) {
        const int b = ch & 1;
        if (ch + 1 < NCH) build(ch + 1, b ^ 1);
        compute(ch, b);
        __syncthreads();
    }

    if (kh == 1) {
        #pragma unroll
        for (int mt = 0; mt < MT; ++mt)
            #pragma unroll
            for (int r = 0; r < 4; ++r) red[rg][mt][r][lane] = acc[mt][r];
    }
    __syncthreads();
    if (kh == 0) {
        #pragma unroll
        for (int mt = 0; mt < MT; ++mt)
            #pragma unroll
            for (int r = 0; r < 4; ++r) acc[mt][r] += red[rg][mt][r][lane];
        if (g4 == 0) srow[rg][col] = acc[4][0];
    }
    __syncthreads();

    if (kh == 0) {
        const float s = srow[rg][col] + cvals[64];
        const int bidx = r0 + col;
        #pragma unroll
        for (int mt = 0; mt < 4; ++mt) {
            f32x4 cv = *(const f32x4*)(cvals + mt * 16 + g4 * 4);
            f32x4 bf = *(const f32x4*)(bfin + mt * 16 + g4 * 4);
            f32x4 ov;
            #pragma unroll
            for (int r = 0; r < 4; ++r) ov[r] = s * (acc[mt][r] + cv[r]) + bf[r];
            *(f32x4*)(out + (size_t)bidx * SDIM + mt * 16 + g4 * 4) = ov;
        }
    }
}

extern "C" void kernel_launch(void* const* d_in, const int* in_sizes, int n_in,
                              void* d_out, int out_size, void* d_ws, size_t ws_size,
                              hipStream_t stream)
{
    const float* z    = (const float*)d_in[0];
    const float* wq   = (const float*)d_in[1];
    const float* bq   = (const float*)d_in[2];
    const float* wk   = (const float*)d_in[3];
    const float* bk   = (const float*)d_in[4];
    const float* Wf   = (const float*)d_in[5];
    const float* bfin = (const float*)d_in[6];
    const int*   midx = (const int*)d_in[7];
    const int F = in_sizes[1];
    float* out = (float*)d_out;

    if (ws_size >= (size_t)WS_NEED) {
        char* ws = (char*)d_ws;
        int*    inv   = (int*)ws;                    // 16 KB
        float*  c     = (float*)(ws + 16384);        // 65 floats
        bf16x8* afrag = (bf16x8*)(ws + 32768);       // 640 KB
        prep_inv  <<<1,   256, 0, stream>>>(midx, F, inv);
        prep_c    <<<65,  64,  0, stream>>>(bq, bk, Wf, F, c);
        prep_afrag<<<160, 256, 0, stream>>>(wq, wk, Wf, inv, F, afrag);
        gemm_ws   <<<256, 256, 0, stream>>>(z, afrag, c, bfin, out);
    } else {
        fused_kernel<<<256, 512, 0, stream>>>(z, wq, bq, wk, bk, Wf, bfin, midx, F, out);
    }
}

// Round 4
// 95.482 us; speedup vs baseline: 1.9244x; 1.3250x over previous
//
#include <hip/hip_runtime.h>
#include <hip/hip_bf16.h>

#define LATENT 4096
#define SDIM   64
#define MT     5              // 5 m-tiles of 16 = 80 rows (64 outputs + s_row + pad)
#define NKS    128            // 4096 / 32 k-steps total
#define KSPLIT 4
#define KSPB   (NKS / KSPLIT) // 32 k-steps per wave
#define WS_NEED (32768 + 40960 * 16)

typedef __bf16 bf16x8 __attribute__((ext_vector_type(8)));
typedef float  f32x4  __attribute__((ext_vector_type(4)));

// ======================= precompute path (needs d_ws) =======================

__global__ void prep_inv(const int* __restrict__ mask_idx, int F, int* __restrict__ inv) {
    int t = threadIdx.x;
    for (int d = t; d < LATENT; d += 256) inv[d] = -1;
    __syncthreads();
    for (int f = t; f < F; f += 256) inv[mask_idx[f]] = f;
}

__global__ void prep_c(const float* __restrict__ bq, const float* __restrict__ bk,
                       const float* __restrict__ Wf, int F, float* __restrict__ c) {
    int o = blockIdx.x, lane = threadIdx.x;
    float p = 0.f;
    if (o < SDIM) { for (int f = lane; f < F; f += 64) p += bk[f] * Wf[o * F + f]; }
    else          { for (int f = lane; f < F; f += 64) p += bq[f]; }
    for (int off = 32; off; off >>= 1) p += __shfl_down(p, off);
    if (lane == 0) c[o] = p;
}

// bf16 A-fragments, fragment-linear: idx = ((ks*5+mt)*64+lane)
__global__ void prep_afrag(const float* __restrict__ wq, const float* __restrict__ wk,
                           const float* __restrict__ Wf, const int* __restrict__ inv,
                           int F, bf16x8* __restrict__ afrag) {
    int g = blockIdx.x * 256 + threadIdx.x;      // 0 .. 40959
    int lane = g & 63;
    int mt = (g >> 6) % 5;
    int ks = g / 320;                            // 0 .. 127
    int m = mt * 16 + (lane & 15);
    int kbase = ks * 32 + (lane >> 4) * 8;
    bf16x8 v;
    #pragma unroll
    for (int j = 0; j < 8; ++j) {
        int f = inv[kbase + j];
        float x = 0.f;
        if (f >= 0) {
            if (m < SDIM) x = wk[f] * Wf[m * F + f];
            else if (m == SDIM) x = wq[f];
        }
        v[j] = (__bf16)x;
    }
    afrag[g] = v;
}

// main: D[80 x 16384] = A[80 x 4096] * z^T.
// 1024 blocks x 256 thr (4 waves). Each block: 16 batch rows; wave kq owns K/4.
// LDS-reduce 4 partials; wave 0 does fused epilogue.
__global__ __launch_bounds__(256, 4) void gemm_ws(
    const float* __restrict__ z, const bf16x8* __restrict__ afrag,
    const float* __restrict__ c, const float* __restrict__ bfin,
    float* __restrict__ out)
{
    __shared__ float red[KSPLIT - 1][MT][4][64];   // 15 KB

    const int tid  = threadIdx.x;
    const int lane = tid & 63;
    const int kq   = tid >> 6;     // K-quarter 0..3
    const int col  = lane & 15;    // batch row within wave (MFMA n / D col)
    const int g4   = lane >> 4;
    const int r0   = blockIdx.x * 16;

    const float*  zp = z + (size_t)(r0 + col) * LATENT + kq * (LATENT / KSPLIT) + g4 * 8;
    const bf16x8* ap = afrag + (size_t)(kq * KSPB * MT) * 64 + lane;

    f32x4 acc[MT] = {};

    // ---- software pipeline: z 2 ahead, afrag 1 ahead, all registers ----
    f32x4 zA0 = *(const f32x4*)(zp +  0), zA1 = *(const f32x4*)(zp +  4);
    f32x4 zB0 = *(const f32x4*)(zp + 32), zB1 = *(const f32x4*)(zp + 36);
    bf16x8 av0 = ap[0], av1 = ap[64], av2 = ap[128], av3 = ap[192], av4 = ap[256];

    #pragma unroll 4
    for (int ks = 0; ks < KSPB; ++ks) {
        f32x4 c0 = zA0, c1 = zA1;
        zA0 = zB0; zA1 = zB1;
        if (ks + 2 < KSPB) {
            zB0 = *(const f32x4*)(zp + (ks + 2) * 32);
            zB1 = *(const f32x4*)(zp + (ks + 2) * 32 + 4);
        }
        bf16x8 b0 = av0, b1 = av1, b2 = av2, b3 = av3, b4 = av4;
        if (ks + 1 < KSPB) {
            const bf16x8* apn = ap + (size_t)((ks + 1) * MT) * 64;
            av0 = apn[0]; av1 = apn[64]; av2 = apn[128]; av3 = apn[192]; av4 = apn[256];
        }
        bf16x8 bv;
        bv[0] = (__bf16)c0[0]; bv[1] = (__bf16)c0[1];
        bv[2] = (__bf16)c0[2]; bv[3] = (__bf16)c0[3];
        bv[4] = (__bf16)c1[0]; bv[5] = (__bf16)c1[1];
        bv[6] = (__bf16)c1[2]; bv[7] = (__bf16)c1[3];
        acc[0] = __builtin_amdgcn_mfma_f32_16x16x32_bf16(b0, bv, acc[0], 0, 0, 0);
        acc[1] = __builtin_amdgcn_mfma_f32_16x16x32_bf16(b1, bv, acc[1], 0, 0, 0);
        acc[2] = __builtin_amdgcn_mfma_f32_16x16x32_bf16(b2, bv, acc[2], 0, 0, 0);
        acc[3] = __builtin_amdgcn_mfma_f32_16x16x32_bf16(b3, bv, acc[3], 0, 0, 0);
        acc[4] = __builtin_amdgcn_mfma_f32_16x16x32_bf16(b4, bv, acc[4], 0, 0, 0);
    }

    // ---- reduce K-quarters ----
    if (kq > 0) {
        #pragma unroll
        for (int mt = 0; mt < MT; ++mt)
            #pragma unroll
            for (int r = 0; r < 4; ++r) red[kq - 1][mt][r][lane] = acc[mt][r];
    }
    __syncthreads();
    if (kq == 0) {
        #pragma unroll
        for (int q = 0; q < KSPLIT - 1; ++q)
            #pragma unroll
            for (int mt = 0; mt < MT; ++mt)
                #pragma unroll
                for (int r = 0; r < 4; ++r) acc[mt][r] += red[q][mt][r][lane];

        // s-row (m=64) lives in acc[4][0] of lanes 0-15; broadcast via shuffle
        const float s = __shfl(acc[4][0], col) + c[SDIM];
        const int b = r0 + col;
        #pragma unroll
        for (int mt = 0; mt < 4; ++mt) {
            f32x4 cv = *(const f32x4*)(c    + mt * 16 + g4 * 4);
            f32x4 bf = *(const f32x4*)(bfin + mt * 16 + g4 * 4);
            f32x4 ov;
            #pragma unroll
            for (int r = 0; r < 4; ++r) ov[r] = s * (acc[mt][r] + cv[r]) + bf[r];
            *(f32x4*)(out + (size_t)b * SDIM + mt * 16 + g4 * 4) = ov;
        }
    }
}

// ================== fused fallback (round-2 kernel, verbatim) ==================
#define BK     128
#define NCH    (LATENT / BK)

__global__ __launch_bounds__(512, 2) void fused_kernel(
    const float* __restrict__ z,
    const float* __restrict__ wq, const float* __restrict__ bq,
    const float* __restrict__ wk, const float* __restrict__ bk,
    const float* __restrict__ Wf, const float* __restrict__ bfin,
    const int* __restrict__ midx, int F,
    float* __restrict__ out)
{
    __shared__ __align__(16) unsigned char ubuf[2 * 80 * BK * 2];
    __shared__ int   inv[LATENT];
    __shared__ float cvals[68];
    __shared__ float srow[4][16];

    __bf16* Ab = (__bf16*)ubuf;
    float (*red)[MT][4][64] = (float (*)[MT][4][64])ubuf;

    const int tid  = threadIdx.x;
    const int lane = tid & 63;
    const int w    = tid >> 6;
    const int rg   = w & 3;
    const int kh   = w >> 2;
    const int r0   = blockIdx.x * 64 + rg * 16;
    const int col  = lane & 15;
    const int g4   = lane >> 4;

    for (int d = tid; d < LATENT; d += 512) inv[d] = -1;
    __syncthreads();
    for (int f = tid; f < F; f += 512) inv[midx[f]] = f;
    {
        const int o = tid >> 3, fo = tid & 7;
        float p = 0.f;
        for (int f = fo; f < F; f += 8) p += bk[f] * Wf[o * F + f];
        p += __shfl_xor(p, 1); p += __shfl_xor(p, 2); p += __shfl_xor(p, 4);
        if (fo == 0) cvals[o] = p;
    }
    if (w == 0) {
        float q = 0.f;
        for (int f = lane; f < F; f += 64) q += bq[f];
        #pragma unroll
        for (int off = 32; off; off >>= 1) q += __shfl_down(q, off);
        if (lane == 0) cvals[64] = q;
    }
    __syncthreads();

    f32x4 acc[MT] = {};

    auto build = [&](int ch, int b) {
        const int k  = tid & 127;
        const int mb = tid >> 7;
        const int f  = inv[ch * BK + k];
        const float wkf = (f >= 0) ? wk[f] : 0.f;
        const float wqf = (f >= 0) ? wq[f] : 0.f;
        __bf16* dst = Ab + b * 80 * BK;
        #pragma unroll
        for (int i = 0; i < 20; ++i) {
            const int m = mb + 4 * i;
            float x = 0.f;
            if (m < SDIM) { if (f >= 0) x = wkf * Wf[m * F + f]; }
            else if (m == SDIM) x = wqf;
            dst[m * BK + (k ^ ((m & 7) << 3))] = (__bf16)x;
        }
    };

    auto compute = [&](int ch, int b) {
        const float* zp = z + (size_t)(r0 + col) * LATENT + ch * BK + kh * 64 + g4 * 8;
        f32x4 za0 = *(const f32x4*)(zp);
        f32x4 za1 = *(const f32x4*)(zp + 4);
        f32x4 zb0 = *(const f32x4*)(zp + 32);
        f32x4 zb1 = *(const f32x4*)(zp + 36);
        const __bf16* src = Ab + b * 80 * BK;
        const int kl0 = kh * 64 + g4 * 8;
        bf16x8 bv;
        bv[0] = (__bf16)za0[0]; bv[1] = (__bf16)za0[1];
        bv[2] = (__bf16)za0[2]; bv[3] = (__bf16)za0[3];
        bv[4] = (__bf16)za1[0]; bv[5] = (__bf16)za1[1];
        bv[6] = (__bf16)za1[2]; bv[7] = (__bf16)za1[3];
        #pragma unroll
        for (int mt = 0; mt < MT; ++mt) {
            const int m = mt * 16 + col;
            bf16x8 av = *(const bf16x8*)(src + m * BK + (kl0 ^ ((m & 7) << 3)));
            acc[mt] = __builtin_amdgcn_mfma_f32_16x16x32_bf16(av, bv, acc[mt], 0, 0, 0);
        }
        const int kl1 = kl0 + 32;
        bv[0] = (__bf16)zb0[0]; bv[1] = (__bf16)zb0[1];
        bv[2] = (__bf16)zb0[2]; bv[3] = (__bf16)zb0[3];
        bv[4] = (__bf16)zb1[0]; bv[5] = (__bf16)zb1[1];
        bv[6] = (__bf16)zb1[2]; bv[7] = (__bf16)zb1[3];
        #pragma unroll
        for (int mt = 0; mt < MT; ++mt) {
            const int m = mt * 16 + col;
            bf16x8 av = *(const bf16x8*)(src + m * BK + (kl1 ^ ((m & 7) << 3)));
            acc[mt] = __builtin_amdgcn_mfma_f32_16x16x32_bf16(av, bv, acc[mt], 0, 0, 0);
        }
    };

    build(0, 0);
    __syncthreads();
    #pragma unroll 2
    for (int ch = 0; ch < NCH; ++ch) {
        const int b = ch & 1;
        if (ch + 1 < NCH) build(ch + 1, b ^ 1);
        compute(ch, b);
        __syncthreads();
    }

    if (kh == 1) {
        #pragma unroll
        for (int mt = 0; mt < MT; ++mt)
            #pragma unroll
            for (int r = 0; r < 4; ++r) red[rg][mt][r][lane] = acc[mt][r];
    }
    __syncthreads();
    if (kh == 0) {
        #pragma unroll
        for (int mt = 0; mt < MT; ++mt)
            #pragma unroll
            for (int r = 0; r < 4; ++r) acc[mt][r] += red[rg][mt][r][lane];
        if (g4 == 0) srow[rg][col] = acc[4][0];
    }
    __syncthreads();

    if (kh == 0) {
        const float s = srow[rg][col] + cvals[64];
        const int bidx = r0 + col;
        #pragma unroll
        for (int mt = 0; mt < 4; ++mt) {
            f32x4 cv = *(const f32x4*)(cvals + mt * 16 + g4 * 4);
            f32x4 bf = *(const f32x4*)(bfin + mt * 16 + g4 * 4);
            f32x4 ov;
            #pragma unroll
            for (int r = 0; r < 4; ++r) ov[r] = s * (acc[mt][r] + cv[r]) + bf[r];
            *(f32x4*)(out + (size_t)bidx * SDIM + mt * 16 + g4 * 4) = ov;
        }
    }
}

extern "C" void kernel_launch(void* const* d_in, const int* in_sizes, int n_in,
                              void* d_out, int out_size, void* d_ws, size_t ws_size,
                              hipStream_t stream)
{
    const float* z    = (const float*)d_in[0];
    const float* wq   = (const float*)d_in[1];
    const float* bq   = (const float*)d_in[2];
    const float* wk   = (const float*)d_in[3];
    const float* bk   = (const float*)d_in[4];
    const float* Wf   = (const float*)d_in[5];
    const float* bfin = (const float*)d_in[6];
    const int*   midx = (const int*)d_in[7];
    const int F = in_sizes[1];
    float* out = (float*)d_out;

    if (ws_size >= (size_t)WS_NEED) {
        char* ws = (char*)d_ws;
        int*    inv   = (int*)ws;                    // 16 KB
        float*  c     = (float*)(ws + 16384);        // 65 floats
        bf16x8* afrag = (bf16x8*)(ws + 32768);       // 640 KB
        prep_inv  <<<1,   256, 0, stream>>>(midx, F, inv);
        prep_c    <<<65,  64,  0, stream>>>(bq, bk, Wf, F, c);
        prep_afrag<<<160, 256, 0, stream>>>(wq, wk, Wf, inv, F, afrag);
        gemm_ws   <<<1024, 256, 0, stream>>>(z, afrag, c, bfin, out);
    } else {
        fused_kernel<<<256, 512, 0, stream>>>(z, wq, bq, wk, bk, Wf, bfin, midx, F, out);
    }
}

// Round 5
// 89.857 us; speedup vs baseline: 2.0449x; 1.0626x over previous
//
#include <hip/hip_runtime.h>
#include <hip/hip_bf16.h>

#define LATENT 4096
#define SDIM   64
#define MT     5              // 5 m-tiles of 16 = 80 rows (64 outputs + s_row + pad)
#define NKS    128            // 4096 / 32 k-steps total
#define KSPLIT 8
#define KSPB   (NKS / KSPLIT) // 16 k-steps per wave
#define WS_NEED (4096 + 40960 * 16)

typedef __bf16 bf16x8 __attribute__((ext_vector_type(8)));
typedef float  f32x4  __attribute__((ext_vector_type(4)));

// ======================= precompute path (needs d_ws) =======================

// c[o] = sum_f bk[f]*W[o,f] (o<64); c[64] = sum_f bq[f]
__global__ void prep_c(const float* __restrict__ bq, const float* __restrict__ bk,
                       const float* __restrict__ Wf, int F, float* __restrict__ c) {
    int o = blockIdx.x, lane = threadIdx.x;
    float p = 0.f;
    if (o < SDIM) { for (int f = lane; f < F; f += 64) p += bk[f] * Wf[o * F + f]; }
    else          { for (int f = lane; f < F; f += 64) p += bq[f]; }
    for (int off = 32; off; off >>= 1) p += __shfl_down(p, off);
    if (lane == 0) c[o] = p;
}

// bf16 A-fragments, fragment-linear: idx = ((ks*5+mt)*64+lane)
// A[m][k]: m<64 -> wk[f]*W[m,f] at masked k (f=inv[k]); m==64 -> wq[f]; else 0
// Self-contained: builds inv[] in LDS per block (no cross-kernel dependency).
__global__ __launch_bounds__(256) void prep_afrag(
    const float* __restrict__ wq, const float* __restrict__ wk,
    const float* __restrict__ Wf, const int* __restrict__ midx,
    int F, bf16x8* __restrict__ afrag)
{
    __shared__ int inv[LATENT];
    const int t = threadIdx.x;
    #pragma unroll
    for (int d = t; d < LATENT; d += 256) inv[d] = -1;
    __syncthreads();
    for (int f = t; f < F; f += 256) inv[midx[f]] = f;
    __syncthreads();

    const int g = blockIdx.x * 256 + t;          // 0 .. 40959
    const int lane = g & 63;
    const int mt = (g >> 6) % 5;
    const int ks = g / 320;                      // 0 .. 127
    const int m = mt * 16 + (lane & 15);
    const int kbase = ks * 32 + (lane >> 4) * 8;
    bf16x8 v;
    #pragma unroll
    for (int j = 0; j < 8; ++j) {
        int f = inv[kbase + j];
        float x = 0.f;
        if (f >= 0) {
            if (m < SDIM) x = wk[f] * Wf[m * F + f];
            else if (m == SDIM) x = wq[f];
        }
        v[j] = (__bf16)x;
    }
    afrag[g] = v;
}

// main: D[80 x 16384] = A[80 x 4096] * z^T.
// 1024 blocks x 512 thr (8 waves) = 32 waves/CU (hardware max occupancy).
// Each block: 16 batch rows; wave w owns K/8 (16 k-steps).
// 3-stage pairwise LDS reduce; wave 0 does the fused epilogue.
__global__ __launch_bounds__(512, 8) void gemm_ws(
    const float* __restrict__ z, const bf16x8* __restrict__ afrag,
    const float* __restrict__ c, const float* __restrict__ bfin,
    float* __restrict__ out)
{
    __shared__ float red[4][MT][4][64];   // 20 KB

    const int tid  = threadIdx.x;
    const int lane = tid & 63;
    const int w    = tid >> 6;     // K-eighth 0..7
    const int col  = lane & 15;    // batch row within wave (MFMA n / D col)
    const int g4   = lane >> 4;
    const int r0   = blockIdx.x * 16;

    const float*  zp = z + (size_t)(r0 + col) * LATENT + w * (LATENT / KSPLIT) + g4 * 8;
    const bf16x8* ap = afrag + (size_t)(w * KSPB * MT) * 64 + lane;

    f32x4 acc[MT] = {};

    // z software-pipelined 1 k-step ahead; afrag loads in-loop (L2-resident,
    // latency hidden by 8 waves/SIMD).
    f32x4 zA0 = *(const f32x4*)(zp), zA1 = *(const f32x4*)(zp + 4);

    #pragma unroll 4
    for (int ks = 0; ks < KSPB; ++ks) {
        f32x4 c0 = zA0, c1 = zA1;
        if (ks + 1 < KSPB) {
            zA0 = *(const f32x4*)(zp + (ks + 1) * 32);
            zA1 = *(const f32x4*)(zp + (ks + 1) * 32 + 4);
        }
        bf16x8 bv;
        bv[0] = (__bf16)c0[0]; bv[1] = (__bf16)c0[1];
        bv[2] = (__bf16)c0[2]; bv[3] = (__bf16)c0[3];
        bv[4] = (__bf16)c1[0]; bv[5] = (__bf16)c1[1];
        bv[6] = (__bf16)c1[2]; bv[7] = (__bf16)c1[3];
        const bf16x8* apk = ap + (size_t)(ks * MT) * 64;
        acc[0] = __builtin_amdgcn_mfma_f32_16x16x32_bf16(apk[0],   bv, acc[0], 0, 0, 0);
        acc[1] = __builtin_amdgcn_mfma_f32_16x16x32_bf16(apk[64],  bv, acc[1], 0, 0, 0);
        acc[2] = __builtin_amdgcn_mfma_f32_16x16x32_bf16(apk[128], bv, acc[2], 0, 0, 0);
        acc[3] = __builtin_amdgcn_mfma_f32_16x16x32_bf16(apk[192], bv, acc[3], 0, 0, 0);
        acc[4] = __builtin_amdgcn_mfma_f32_16x16x32_bf16(apk[256], bv, acc[4], 0, 0, 0);
    }

    // ---- 3-stage pairwise reduce across the 8 K-eighths ----
    // stage 1: w4..7 -> red[0..3]; w0..3 absorb
    if (w >= 4) {
        #pragma unroll
        for (int mt = 0; mt < MT; ++mt)
            #pragma unroll
            for (int r = 0; r < 4; ++r) red[w - 4][mt][r][lane] = acc[mt][r];
    }
    __syncthreads();
    if (w < 4) {
        #pragma unroll
        for (int mt = 0; mt < MT; ++mt)
            #pragma unroll
            for (int r = 0; r < 4; ++r) acc[mt][r] += red[w][mt][r][lane];
    }
    __syncthreads();
    // stage 2: w2..3 -> red[0..1]; w0..1 absorb
    if (w == 2 || w == 3) {
        #pragma unroll
        for (int mt = 0; mt < MT; ++mt)
            #pragma unroll
            for (int r = 0; r < 4; ++r) red[w - 2][mt][r][lane] = acc[mt][r];
    }
    __syncthreads();
    if (w < 2) {
        #pragma unroll
        for (int mt = 0; mt < MT; ++mt)
            #pragma unroll
            for (int r = 0; r < 4; ++r) acc[mt][r] += red[w][mt][r][lane];
    }
    __syncthreads();
    // stage 3: w1 -> red[0]; w0 absorbs + epilogue
    if (w == 1) {
        #pragma unroll
        for (int mt = 0; mt < MT; ++mt)
            #pragma unroll
            for (int r = 0; r < 4; ++r) red[0][mt][r][lane] = acc[mt][r];
    }
    __syncthreads();
    if (w == 0) {
        #pragma unroll
        for (int mt = 0; mt < MT; ++mt)
            #pragma unroll
            for (int r = 0; r < 4; ++r) acc[mt][r] += red[0][mt][r][lane];

        // s-row (m=64) lives in acc[4][0] of lanes 0-15; broadcast via shuffle
        const float s = __shfl(acc[4][0], col) + c[SDIM];
        const int b = r0 + col;
        #pragma unroll
        for (int mt = 0; mt < 4; ++mt) {
            f32x4 cv = *(const f32x4*)(c    + mt * 16 + g4 * 4);
            f32x4 bf = *(const f32x4*)(bfin + mt * 16 + g4 * 4);
            f32x4 ov;
            #pragma unroll
            for (int r = 0; r < 4; ++r) ov[r] = s * (acc[mt][r] + cv[r]) + bf[r];
            *(f32x4*)(out + (size_t)b * SDIM + mt * 16 + g4 * 4) = ov;
        }
    }
}

// ================== fused fallback (round-2 kernel, verbatim) ==================
#define BK     128
#define NCH    (LATENT / BK)

__global__ __launch_bounds__(512, 2) void fused_kernel(
    const float* __restrict__ z,
    const float* __restrict__ wq, const float* __restrict__ bq,
    const float* __restrict__ wk, const float* __restrict__ bk,
    const float* __restrict__ Wf, const float* __restrict__ bfin,
    const int* __restrict__ midx, int F,
    float* __restrict__ out)
{
    __shared__ __align__(16) unsigned char ubuf[2 * 80 * BK * 2];
    __shared__ int   inv[LATENT];
    __shared__ float cvals[68];
    __shared__ float srow[4][16];

    __bf16* Ab = (__bf16*)ubuf;
    float (*red)[MT][4][64] = (float (*)[MT][4][64])ubuf;

    const int tid  = threadIdx.x;
    const int lane = tid & 63;
    const int w    = tid >> 6;
    const int rg   = w & 3;
    const int kh   = w >> 2;
    const int r0   = blockIdx.x * 64 + rg * 16;
    const int col  = lane & 15;
    const int g4   = lane >> 4;

    for (int d = tid; d < LATENT; d += 512) inv[d] = -1;
    __syncthreads();
    for (int f = tid; f < F; f += 512) inv[midx[f]] = f;
    {
        const int o = tid >> 3, fo = tid & 7;
        float p = 0.f;
        for (int f = fo; f < F; f += 8) p += bk[f] * Wf[o * F + f];
        p += __shfl_xor(p, 1); p += __shfl_xor(p, 2); p += __shfl_xor(p, 4);
        if (fo == 0) cvals[o] = p;
    }
    if (w == 0) {
        float q = 0.f;
        for (int f = lane; f < F; f += 64) q += bq[f];
        #pragma unroll
        for (int off = 32; off; off >>= 1) q += __shfl_down(q, off);
        if (lane == 0) cvals[64] = q;
    }
    __syncthreads();

    f32x4 acc[MT] = {};

    auto build = [&](int ch, int b) {
        const int k  = tid & 127;
        const int mb = tid >> 7;
        const int f  = inv[ch * BK + k];
        const float wkf = (f >= 0) ? wk[f] : 0.f;
        const float wqf = (f >= 0) ? wq[f] : 0.f;
        __bf16* dst = Ab + b * 80 * BK;
        #pragma unroll
        for (int i = 0; i < 20; ++i) {
            const int m = mb + 4 * i;
            float x = 0.f;
            if (m < SDIM) { if (f >= 0) x = wkf * Wf[m * F + f]; }
            else if (m == SDIM) x = wqf;
            dst[m * BK + (k ^ ((m & 7) << 3))] = (__bf16)x;
        }
    };

    auto compute = [&](int ch, int b) {
        const float* zp = z + (size_t)(r0 + col) * LATENT + ch * BK + kh * 64 + g4 * 8;
        f32x4 za0 = *(const f32x4*)(zp);
        f32x4 za1 = *(const f32x4*)(zp + 4);
        f32x4 zb0 = *(const f32x4*)(zp + 32);
        f32x4 zb1 = *(const f32x4*)(zp + 36);
        const __bf16* src = Ab + b * 80 * BK;
        const int kl0 = kh * 64 + g4 * 8;
        bf16x8 bv;
        bv[0] = (__bf16)za0[0]; bv[1] = (__bf16)za0[1];
        bv[2] = (__bf16)za0[2]; bv[3] = (__bf16)za0[3];
        bv[4] = (__bf16)za1[0]; bv[5] = (__bf16)za1[1];
        bv[6] = (__bf16)za1[2]; bv[7] = (__bf16)za1[3];
        #pragma unroll
        for (int mt = 0; mt < MT; ++mt) {
            const int m = mt * 16 + col;
            bf16x8 av = *(const bf16x8*)(src + m * BK + (kl0 ^ ((m & 7) << 3)));
            acc[mt] = __builtin_amdgcn_mfma_f32_16x16x32_bf16(av, bv, acc[mt], 0, 0, 0);
        }
        const int kl1 = kl0 + 32;
        bv[0] = (__bf16)zb0[0]; bv[1] = (__bf16)zb0[1];
        bv[2] = (__bf16)zb0[2]; bv[3] = (__bf16)zb0[3];
        bv[4] = (__bf16)zb1[0]; bv[5] = (__bf16)zb1[1];
        bv[6] = (__bf16)zb1[2]; bv[7] = (__bf16)zb1[3];
        #pragma unroll
        for (int mt = 0; mt < MT; ++mt) {
            const int m = mt * 16 + col;
            bf16x8 av = *(const bf16x8*)(src + m * BK + (kl1 ^ ((m & 7) << 3)));
            acc[mt] = __builtin_amdgcn_mfma_f32_16x16x32_bf16(av, bv, acc[mt], 0, 0, 0);
        }
    };

    build(0, 0);
    __syncthreads();
    #pragma unroll 2
    for (int ch = 0; ch < NCH; ++ch) {
        const int b = ch & 1;
        if (ch + 1 < NCH) build(ch + 1, b ^ 1);
        compute(ch, b);
        __syncthreads();
    }

    if (kh == 1) {
        #pragma unroll
        for (int mt = 0; mt < MT; ++mt)
            #pragma unroll
            for (int r = 0; r < 4; ++r) red[rg][mt][r][lane] = acc[mt][r];
    }
    __syncthreads();
    if (kh == 0) {
        #pragma unroll
        for (int mt = 0; mt < MT; ++mt)
            #pragma unroll
            for (int r = 0; r < 4; ++r) acc[mt][r] += red[rg][mt][r][lane];
        if (g4 == 0) srow[rg][col] = acc[4][0];
    }
    __syncthreads();

    if (kh == 0) {
        const float s = srow[rg][col] + cvals[64];
        const int bidx = r0 + col;
        #pragma unroll
        for (int mt = 0; mt < 4; ++mt) {
            f32x4 cv = *(const f32x4*)(cvals + mt * 16 + g4 * 4);
            f32x4 bf = *(const f32x4*)(bfin + mt * 16 + g4 * 4);
            f32x4 ov;
            #pragma unroll
            for (int r = 0; r < 4; ++r) ov[r] = s * (acc[mt][r] + cv[r]) + bf[r];
            *(f32x4*)(out + (size_t)bidx * SDIM + mt * 16 + g4 * 4) = ov;
        }
    }
}

extern "C" void kernel_launch(void* const* d_in, const int* in_sizes, int n_in,
                              void* d_out, int out_size, void* d_ws, size_t ws_size,
                              hipStream_t stream)
{
    const float* z    = (const float*)d_in[0];
    const float* wq   = (const float*)d_in[1];
    const float* bq   = (const float*)d_in[2];
    const float* wk   = (const float*)d_in[3];
    const float* bk   = (const float*)d_in[4];
    const float* Wf   = (const float*)d_in[5];
    const float* bfin = (const float*)d_in[6];
    const int*   midx = (const int*)d_in[7];
    const int F = in_sizes[1];
    float* out = (float*)d_out;

    if (ws_size >= (size_t)WS_NEED) {
        char* ws = (char*)d_ws;
        float*  c     = (float*)ws;                  // 65 floats
        bf16x8* afrag = (bf16x8*)(ws + 4096);        // 640 KB
        prep_c    <<<65,  64,  0, stream>>>(bq, bk, Wf, F, c);
        prep_afrag<<<160, 256, 0, stream>>>(wq, wk, Wf, midx, F, afrag);
        gemm_ws   <<<1024, 512, 0, stream>>>(z, afrag, c, bfin, out);
    } else {
        fused_kernel<<<256, 512, 0, stream>>>(z, wq, bq, wk, bk, Wf, bfin, midx, F, out);
    }
}

// Round 6
// 83.112 us; speedup vs baseline: 2.2109x; 1.0812x over previous
//
#include <hip/hip_runtime.h>
#include <hip/hip_bf16.h>

#define LATENT 4096
#define SDIM   64
#define MT     5              // 5 m-tiles of 16 = 80 rows (64 outputs + s_row + pad)
#define CHUNK  256            // floats of K staged per chunk
#define NCHK   (LATENT / CHUNK)   // 16 chunks
#define ROWPAD 260            // padded LDS row stride (floats): bank-friendly, 16B-aligned
#define WS_NEED (4096 + 40960 * 16)

typedef __bf16 bf16x8 __attribute__((ext_vector_type(8)));
typedef float  f32x4  __attribute__((ext_vector_type(4)));

#define GLOBAL_AS __attribute__((address_space(1)))
#define LDS_AS    __attribute__((address_space(3)))

__device__ __forceinline__ void load_lds16(const float* g, float* l) {
    // DMA 16B/lane: LDS dest = wave-uniform base + lane*16 (linear); global src per-lane.
    __builtin_amdgcn_global_load_lds((const GLOBAL_AS void*)g, (LDS_AS void*)l, 16, 0, 0);
}

// ======================= precompute path (needs d_ws) =======================

// c[o] = sum_f bk[f]*W[o,f] (o<64); c[64] = sum_f bq[f]
__global__ void prep_c(const float* __restrict__ bq, const float* __restrict__ bk,
                       const float* __restrict__ Wf, int F, float* __restrict__ c) {
    int o = blockIdx.x, lane = threadIdx.x;
    float p = 0.f;
    if (o < SDIM) { for (int f = lane; f < F; f += 64) p += bk[f] * Wf[o * F + f]; }
    else          { for (int f = lane; f < F; f += 64) p += bq[f]; }
    for (int off = 32; off; off >>= 1) p += __shfl_down(p, off);
    if (lane == 0) c[o] = p;
}

// bf16 A-fragments, fragment-linear: idx = ((ks*5+mt)*64+lane)
// A[m][k]: m<64 -> wk[f]*W[m,f] at masked k (f=inv[k]); m==64 -> wq[f]; else 0
__global__ __launch_bounds__(256) void prep_afrag(
    const float* __restrict__ wq, const float* __restrict__ wk,
    const float* __restrict__ Wf, const int* __restrict__ midx,
    int F, bf16x8* __restrict__ afrag)
{
    __shared__ int inv[LATENT];
    const int t = threadIdx.x;
    #pragma unroll
    for (int d = t; d < LATENT; d += 256) inv[d] = -1;
    __syncthreads();
    for (int f = t; f < F; f += 256) inv[midx[f]] = f;
    __syncthreads();

    const int g = blockIdx.x * 256 + t;          // 0 .. 40959
    const int lane = g & 63;
    const int mt = (g >> 6) % 5;
    const int ks = g / 320;                      // 0 .. 127
    const int m = mt * 16 + (lane & 15);
    const int kbase = ks * 32 + (lane >> 4) * 8;
    bf16x8 v;
    #pragma unroll
    for (int j = 0; j < 8; ++j) {
        int f = inv[kbase + j];
        float x = 0.f;
        if (f >= 0) {
            if (m < SDIM) x = wk[f] * Wf[m * F + f];
            else if (m == SDIM) x = wq[f];
        }
        v[j] = (__bf16)x;
    }
    afrag[g] = v;
}

// main: D[80 x 16384] = A[80 x 4096] * z^T.
// 1024 blocks x 512 thr (8 waves), 16 batch rows per block.
// z staged per 256-float chunk via global_load_lds (double-buffered, padded rows);
// wave w consumes k-step w of each chunk; 3-stage LDS reduce; wave 0 epilogue.
__global__ __launch_bounds__(512, 8) void gemm_lds(
    const float* __restrict__ z, const bf16x8* __restrict__ afrag,
    const float* __restrict__ c, const float* __restrict__ bfin,
    float* __restrict__ out)
{
    __shared__ __align__(16) char smem[2 * 16 * ROWPAD * 4];   // 33280 B
    float (*lds)[16][ROWPAD] = (float (*)[16][ROWPAD])smem;    // staging view
    float (*red)[MT][4][64]  = (float (*)[MT][4][64])smem;     // reduce view (reuse)

    const int tid  = threadIdx.x;
    const int lane = tid & 63;
    const int w    = tid >> 6;     // wave 0..7 (= k-step within chunk)
    const int col  = lane & 15;    // batch row within tile (MFMA n / D col)
    const int g4   = lane >> 4;
    const int r0   = blockIdx.x * 16;

    const float* zrow0 = z + (size_t)(r0 + w)     * LATENT;
    const float* zrow1 = z + (size_t)(r0 + 8 + w) * LATENT;

    f32x4 acc[MT] = {};

    // stage chunk cN into buffer q: wave w DMAs row w and row 8+w (1KB each, contiguous)
    auto stage = [&](int cN, int q) {
        load_lds16(zrow0 + cN * CHUNK + lane * 4, &lds[q][w][0]);
        load_lds16(zrow1 + cN * CHUNK + lane * 4, &lds[q][8 + w][0]);
    };

    // consume chunk cN from buffer q: this wave's k-step is w
    auto consume = [&](int cN, int q) {
        const float* p = &lds[q][col][w * 32 + g4 * 8];
        f32x4 a = *(const f32x4*)p;
        f32x4 b = *(const f32x4*)(p + 4);
        bf16x8 bv;
        bv[0] = (__bf16)a[0]; bv[1] = (__bf16)a[1];
        bv[2] = (__bf16)a[2]; bv[3] = (__bf16)a[3];
        bv[4] = (__bf16)b[0]; bv[5] = (__bf16)b[1];
        bv[6] = (__bf16)b[2]; bv[7] = (__bf16)b[3];
        const bf16x8* apk = afrag + (size_t)((cN * 8 + w) * MT) * 64 + lane;
        acc[0] = __builtin_amdgcn_mfma_f32_16x16x32_bf16(apk[0],   bv, acc[0], 0, 0, 0);
        acc[1] = __builtin_amdgcn_mfma_f32_16x16x32_bf16(apk[64],  bv, acc[1], 0, 0, 0);
        acc[2] = __builtin_amdgcn_mfma_f32_16x16x32_bf16(apk[128], bv, acc[2], 0, 0, 0);
        acc[3] = __builtin_amdgcn_mfma_f32_16x16x32_bf16(apk[192], bv, acc[3], 0, 0, 0);
        acc[4] = __builtin_amdgcn_mfma_f32_16x16x32_bf16(apk[256], bv, acc[4], 0, 0, 0);
    };

    stage(0, 0);
    __syncthreads();
    for (int cN = 0; cN < NCHK; ++cN) {
        const int q = cN & 1;
        if (cN + 1 < NCHK) stage(cN + 1, q ^ 1);   // issue next-chunk DMA first
        consume(cN, q);
        __syncthreads();   // drains gload_lds (compiler vmcnt) + protects buffer reuse
    }

    // ---- 3-stage pairwise reduce across the 8 k-step groups (smem reused) ----
    if (w >= 4) {
        #pragma unroll
        for (int mt = 0; mt < MT; ++mt)
            #pragma unroll
            for (int r = 0; r < 4; ++r) red[w - 4][mt][r][lane] = acc[mt][r];
    }
    __syncthreads();
    if (w < 4) {
        #pragma unroll
        for (int mt = 0; mt < MT; ++mt)
            #pragma unroll
            for (int r = 0; r < 4; ++r) acc[mt][r] += red[w][mt][r][lane];
    }
    __syncthreads();
    if (w == 2 || w == 3) {
        #pragma unroll
        for (int mt = 0; mt < MT; ++mt)
            #pragma unroll
            for (int r = 0; r < 4; ++r) red[w - 2][mt][r][lane] = acc[mt][r];
    }
    __syncthreads();
    if (w < 2) {
        #pragma unroll
        for (int mt = 0; mt < MT; ++mt)
            #pragma unroll
            for (int r = 0; r < 4; ++r) acc[mt][r] += red[w][mt][r][lane];
    }
    __syncthreads();
    if (w == 1) {
        #pragma unroll
        for (int mt = 0; mt < MT; ++mt)
            #pragma unroll
            for (int r = 0; r < 4; ++r) red[0][mt][r][lane] = acc[mt][r];
    }
    __syncthreads();
    if (w == 0) {
        #pragma unroll
        for (int mt = 0; mt < MT; ++mt)
            #pragma unroll
            for (int r = 0; r < 4; ++r) acc[mt][r] += red[0][mt][r][lane];

        // s-row (m=64) lives in acc[4][0] of lanes 0-15; broadcast via shuffle
        const float s = __shfl(acc[4][0], col) + c[SDIM];
        const int b = r0 + col;
        #pragma unroll
        for (int mt = 0; mt < 4; ++mt) {
            f32x4 cv = *(const f32x4*)(c    + mt * 16 + g4 * 4);
            f32x4 bf = *(const f32x4*)(bfin + mt * 16 + g4 * 4);
            f32x4 ov;
            #pragma unroll
            for (int r = 0; r < 4; ++r) ov[r] = s * (acc[mt][r] + cv[r]) + bf[r];
            *(f32x4*)(out + (size_t)b * SDIM + mt * 16 + g4 * 4) = ov;
        }
    }
}

// ================== fused fallback (round-2 kernel, verbatim) ==================
#define BK     128
#define NCH    (LATENT / BK)

__global__ __launch_bounds__(512, 2) void fused_kernel(
    const float* __restrict__ z,
    const float* __restrict__ wq, const float* __restrict__ bq,
    const float* __restrict__ wk, const float* __restrict__ bk,
    const float* __restrict__ Wf, const float* __restrict__ bfin,
    const int* __restrict__ midx, int F,
    float* __restrict__ out)
{
    __shared__ __align__(16) unsigned char ubuf[2 * 80 * BK * 2];
    __shared__ int   inv[LATENT];
    __shared__ float cvals[68];
    __shared__ float srow[4][16];

    __bf16* Ab = (__bf16*)ubuf;
    float (*red)[MT][4][64] = (float (*)[MT][4][64])ubuf;

    const int tid  = threadIdx.x;
    const int lane = tid & 63;
    const int w    = tid >> 6;
    const int rg   = w & 3;
    const int kh   = w >> 2;
    const int r0   = blockIdx.x * 64 + rg * 16;
    const int col  = lane & 15;
    const int g4   = lane >> 4;

    for (int d = tid; d < LATENT; d += 512) inv[d] = -1;
    __syncthreads();
    for (int f = tid; f < F; f += 512) inv[midx[f]] = f;
    {
        const int o = tid >> 3, fo = tid & 7;
        float p = 0.f;
        for (int f = fo; f < F; f += 8) p += bk[f] * Wf[o * F + f];
        p += __shfl_xor(p, 1); p += __shfl_xor(p, 2); p += __shfl_xor(p, 4);
        if (fo == 0) cvals[o] = p;
    }
    if (w == 0) {
        float q = 0.f;
        for (int f = lane; f < F; f += 64) q += bq[f];
        #pragma unroll
        for (int off = 32; off; off >>= 1) q += __shfl_down(q, off);
        if (lane == 0) cvals[64] = q;
    }
    __syncthreads();

    f32x4 acc[MT] = {};

    auto build = [&](int ch, int b) {
        const int k  = tid & 127;
        const int mb = tid >> 7;
        const int f  = inv[ch * BK + k];
        const float wkf = (f >= 0) ? wk[f] : 0.f;
        const float wqf = (f >= 0) ? wq[f] : 0.f;
        __bf16* dst = Ab + b * 80 * BK;
        #pragma unroll
        for (int i = 0; i < 20; ++i) {
            const int m = mb + 4 * i;
            float x = 0.f;
            if (m < SDIM) { if (f >= 0) x = wkf * Wf[m * F + f]; }
            else if (m == SDIM) x = wqf;
            dst[m * BK + (k ^ ((m & 7) << 3))] = (__bf16)x;
        }
    };

    auto compute = [&](int ch, int b) {
        const float* zp = z + (size_t)(r0 + col) * LATENT + ch * BK + kh * 64 + g4 * 8;
        f32x4 za0 = *(const f32x4*)(zp);
        f32x4 za1 = *(const f32x4*)(zp + 4);
        f32x4 zb0 = *(const f32x4*)(zp + 32);
        f32x4 zb1 = *(const f32x4*)(zp + 36);
        const __bf16* src = Ab + b * 80 * BK;
        const int kl0 = kh * 64 + g4 * 8;
        bf16x8 bv;
        bv[0] = (__bf16)za0[0]; bv[1] = (__bf16)za0[1];
        bv[2] = (__bf16)za0[2]; bv[3] = (__bf16)za0[3];
        bv[4] = (__bf16)za1[0]; bv[5] = (__bf16)za1[1];
        bv[6] = (__bf16)za1[2]; bv[7] = (__bf16)za1[3];
        #pragma unroll
        for (int mt = 0; mt < MT; ++mt) {
            const int m = mt * 16 + col;
            bf16x8 av = *(const bf16x8*)(src + m * BK + (kl0 ^ ((m & 7) << 3)));
            acc[mt] = __builtin_amdgcn_mfma_f32_16x16x32_bf16(av, bv, acc[mt], 0, 0, 0);
        }
        const int kl1 = kl0 + 32;
        bv[0] = (__bf16)zb0[0]; bv[1] = (__bf16)zb0[1];
        bv[2] = (__bf16)zb0[2]; bv[3] = (__bf16)zb0[3];
        bv[4] = (__bf16)zb1[0]; bv[5] = (__bf16)zb1[1];
        bv[6] = (__bf16)zb1[2]; bv[7] = (__bf16)zb1[3];
        #pragma unroll
        for (int mt = 0; mt < MT; ++mt) {
            const int m = mt * 16 + col;
            bf16x8 av = *(const bf16x8*)(src + m * BK + (kl1 ^ ((m & 7) << 3)));
            acc[mt] = __builtin_amdgcn_mfma_f32_16x16x32_bf16(av, bv, acc[mt], 0, 0, 0);
        }
    };

    build(0, 0);
    __syncthreads();
    #pragma unroll 2
    for (int ch = 0; ch < NCH; ++ch) {
        const int b = ch & 1;
        if (ch + 1 < NCH) build(ch + 1, b ^ 1);
        compute(ch, b);
        __syncthreads();
    }

    if (kh == 1) {
        #pragma unroll
        for (int mt = 0; mt < MT; ++mt)
            #pragma unroll
            for (int r = 0; r < 4; ++r) red[rg][mt][r][lane] = acc[mt][r];
    }
    __syncthreads();
    if (kh == 0) {
        #pragma unroll
        for (int mt = 0; mt < MT; ++mt)
            #pragma unroll
            for (int r = 0; r < 4; ++r) acc[mt][r] += red[rg][mt][r][lane];
        if (g4 == 0) srow[rg][col] = acc[4][0];
    }
    __syncthreads();

    if (kh == 0) {
        const float s = srow[rg][col] + cvals[64];
        const int bidx = r0 + col;
        #pragma unroll
        for (int mt = 0; mt < 4; ++mt) {
            f32x4 cv = *(const f32x4*)(cvals + mt * 16 + g4 * 4);
            f32x4 bf = *(const f32x4*)(bfin + mt * 16 + g4 * 4);
            f32x4 ov;
            #pragma unroll
            for (int r = 0; r < 4; ++r) ov[r] = s * (acc[mt][r] + cv[r]) + bf[r];
            *(f32x4*)(out + (size_t)bidx * SDIM + mt * 16 + g4 * 4) = ov;
        }
    }
}

extern "C" void kernel_launch(void* const* d_in, const int* in_sizes, int n_in,
                              void* d_out, int out_size, void* d_ws, size_t ws_size,
                              hipStream_t stream)
{
    const float* z    = (const float*)d_in[0];
    const float* wq   = (const float*)d_in[1];
    const float* bq   = (const float*)d_in[2];
    const float* wk   = (const float*)d_in[3];
    const float* bk   = (const float*)d_in[4];
    const float* Wf   = (const float*)d_in[5];
    const float* bfin = (const float*)d_in[6];
    const int*   midx = (const int*)d_in[7];
    const int F = in_sizes[1];
    float* out = (float*)d_out;

    if (ws_size >= (size_t)WS_NEED) {
        char* ws = (char*)d_ws;
        float*  c     = (float*)ws;                  // 65 floats
        bf16x8* afrag = (bf16x8*)(ws + 4096);        // 640 KB
        prep_c    <<<65,  64,  0, stream>>>(bq, bk, Wf, F, c);
        prep_afrag<<<160, 256, 0, stream>>>(wq, wk, Wf, midx, F, afrag);
        gemm_lds  <<<1024, 512, 0, stream>>>(z, afrag, c, bfin, out);
    } else {
        fused_kernel<<<256, 512, 0, stream>>>(z, wq, bq, wk, bk, Wf, bfin, midx, F, out);
    }
}

// Round 9
// 80.070 us; speedup vs baseline: 2.2949x; 1.0380x over previous
//
#include <hip/hip_runtime.h>
#include <hip/hip_bf16.h>

#define LATENT 4096
#define SDIM   64
#define MT     5              // 5 m-tiles of 16 = 80 rows (64 outputs + s_row + pad)
#define CHUNK  128            // floats of K per staged chunk (= 4 k-steps)
#define NCHK   (LATENT / CHUNK)   // 32
#define NBUF   4
#define ROWS   32             // batch rows per block
#define WS_NEED (4096 + 40960 * 16)

typedef __bf16 bf16x8 __attribute__((ext_vector_type(8)));
typedef float  f32x4  __attribute__((ext_vector_type(4)));

#define GLOBAL_AS __attribute__((address_space(1)))
#define LDS_AS    __attribute__((address_space(3)))

__device__ __forceinline__ void load_lds16(const float* g, float* l) {
    __builtin_amdgcn_global_load_lds((const GLOBAL_AS void*)g, (LDS_AS void*)l, 16, 0, 0);
}

#define WAITB(N) do { asm volatile("s_waitcnt vmcnt(" #N ")" ::: "memory"); \
                      __builtin_amdgcn_s_barrier(); } while (0)

// ======================= precompute path (needs d_ws) =======================

__global__ void prep_c(const float* __restrict__ bq, const float* __restrict__ bk,
                       const float* __restrict__ Wf, int F, float* __restrict__ c) {
    int o = blockIdx.x, lane = threadIdx.x;
    float p = 0.f;
    if (o < SDIM) { for (int f = lane; f < F; f += 64) p += bk[f] * Wf[o * F + f]; }
    else          { for (int f = lane; f < F; f += 64) p += bq[f]; }
    for (int off = 32; off; off >>= 1) p += __shfl_down(p, off);
    if (lane == 0) c[o] = p;
}

// bf16 A-fragments, fragment-linear: idx = ((ks*5+mt)*64+lane)
__global__ __launch_bounds__(256) void prep_afrag(
    const float* __restrict__ wq, const float* __restrict__ wk,
    const float* __restrict__ Wf, const int* __restrict__ midx,
    int F, bf16x8* __restrict__ afrag)
{
    __shared__ int inv[LATENT];
    const int t = threadIdx.x;
    #pragma unroll
    for (int d = t; d < LATENT; d += 256) inv[d] = -1;
    __syncthreads();
    for (int f = t; f < F; f += 256) inv[midx[f]] = f;
    __syncthreads();

    const int g = blockIdx.x * 256 + t;          // 0 .. 40959
    const int lane = g & 63;
    const int mt = (g >> 6) % 5;
    const int ks = g / 320;                      // 0 .. 127
    const int m = mt * 16 + (lane & 15);
    const int kbase = ks * 32 + (lane >> 4) * 8;
    bf16x8 v;
    #pragma unroll
    for (int j = 0; j < 8; ++j) {
        int f = inv[kbase + j];
        float x = 0.f;
        if (f >= 0) {
            if (m < SDIM) x = wk[f] * Wf[m * F + f];
            else if (m == SDIM) x = wq[f];
        }
        v[j] = (__bf16)x;
    }
    afrag[g] = v;
}

struct AF { bf16x8 a0, a1, a2, a3, a4; };

// main: D[80 x 16384] = A[80 x 4096] * z^T, counted-vmcnt ring pipeline.
// 512 blocks x 256 thr (4 waves); 32 rows/block; wave w = k-step w of each chunk.
// Wave w stages LDS rows 8w..8w+7 (4 x 1KB gload_lds). LDS 16B-XOR swizzled
// (global-source side pre-swizzled; read side applies same XOR) -> 2-way banks.
__global__ __launch_bounds__(256, 2) void gemm_pipe(
    const float* __restrict__ z, const bf16x8* __restrict__ afrag,
    const float* __restrict__ c, const float* __restrict__ bfin,
    float* __restrict__ out)
{
    __shared__ __align__(16) float zbuf[NBUF][ROWS][CHUNK];   // 64 KB
    float (*red)[2][MT][4][64] = (float (*)[2][MT][4][64])zbuf;  // [grp][ng][mt][r][lane]

    const int tid  = threadIdx.x;
    const int lane = tid & 63;
    const int w    = tid >> 6;     // 0..3 = k-step within chunk
    const int col  = lane & 15;
    const int g4   = lane >> 4;
    const int r0   = blockIdx.x * ROWS;
    const int ra   = 8 * w;        // this wave stages LDS rows ra..ra+7

    // global sources for the 4 staging instrs; column pre-swizzled so that
    // LDS float pos p (linear dest) holds z col (p ^ ((ldsrow&7)<<2)).
    const int half  = lane >> 5;          // 0..1 (row within a 2-row pair)
    const int cbase = (lane & 31) * 4;    // 16B slot within row
    const float* zsrc[4];
    #pragma unroll
    for (int j = 0; j < 4; ++j) {
        const int lrow = ra + 2 * j + half;               // LDS row 0..31
        zsrc[j] = z + (size_t)(r0 + lrow) * LATENT + (cbase ^ ((lrow & 7) << 2));
    }

    f32x4 acc[2][MT] = {};

    auto stage = [&](int cN) {   // 4 VMEM ops
        float* d = &zbuf[cN & 3][ra][0];
        load_lds16(zsrc[0] + cN * CHUNK, d);
        load_lds16(zsrc[1] + cN * CHUNK, d + 256);
        load_lds16(zsrc[2] + cN * CHUNK, d + 512);
        load_lds16(zsrc[3] + cN * CHUNK, d + 768);
    };
    auto loadA = [&](int cN, AF& Fr) {   // 5 VMEM ops
        const bf16x8* p = afrag + (size_t)((cN * 4 + w) * MT) * 64 + lane;
        Fr.a0 = p[0]; Fr.a1 = p[64]; Fr.a2 = p[128]; Fr.a3 = p[192]; Fr.a4 = p[256];
    };
    auto consume = [&](int cN, const AF& Fr) {
        const int q = cN & 3;
        const int base = w * 32 + g4 * 8;          // multiple of 8
        const int b0 = base ^ ((col & 7) << 2);    // 16B-aligned (b0 % 4 == 0)
        #pragma unroll
        for (int ng = 0; ng < 2; ++ng) {
            const float* pr = &zbuf[q][ng * 16 + col][0];
            f32x4 a = *(const f32x4*)(pr + b0);
            f32x4 b = *(const f32x4*)(pr + (b0 ^ 4));
            bf16x8 bv;
            bv[0] = (__bf16)a[0]; bv[1] = (__bf16)a[1];
            bv[2] = (__bf16)a[2]; bv[3] = (__bf16)a[3];
            bv[4] = (__bf16)b[0]; bv[5] = (__bf16)b[1];
            bv[6] = (__bf16)b[2]; bv[7] = (__bf16)b[3];
            acc[ng][0] = __builtin_amdgcn_mfma_f32_16x16x32_bf16(Fr.a0, bv, acc[ng][0], 0, 0, 0);
            acc[ng][1] = __builtin_amdgcn_mfma_f32_16x16x32_bf16(Fr.a1, bv, acc[ng][1], 0, 0, 0);
            acc[ng][2] = __builtin_amdgcn_mfma_f32_16x16x32_bf16(Fr.a2, bv, acc[ng][2], 0, 0, 0);
            acc[ng][3] = __builtin_amdgcn_mfma_f32_16x16x32_bf16(Fr.a3, bv, acc[ng][3], 0, 0, 0);
            acc[ng][4] = __builtin_amdgcn_mfma_f32_16x16x32_bf16(Fr.a4, bv, acc[ng][4], 0, 0, 0);
        }
    };

    AF fA, fB;
    // ledger of outstanding VMEM ops (per wave):
    stage(0); stage(1); loadA(0, fA);              // 4+4+5 = 13
    for (int cN = 0; cN < NCHK - 4; cN += 2) {
        loadA(cN + 1, fB); stage(cN + 2);          // +9
        WAITB(9);                                  // retire all but newest 9
        consume(cN, fA);
        loadA(cN + 2, fA); stage(cN + 3);          // +9 (-> 18)
        WAITB(9);
        consume(cN + 1, fB);
    }
    // after loop: outstanding 9 = loadA(28)+stage(29)
    loadA(29, fB); stage(30); WAITB(9); consume(28, fA);
    loadA(30, fA); stage(31); WAITB(9); consume(29, fB);
    loadA(31, fB);            WAITB(5); consume(30, fA);
                              WAITB(0); consume(31, fB);

    // ---- reduce the 4 k-phase partials (zbuf reused; barrier protects) ----
    __syncthreads();
    if (w >= 2) {
        #pragma unroll
        for (int ng = 0; ng < 2; ++ng)
            #pragma unroll
            for (int mt = 0; mt < MT; ++mt)
                #pragma unroll
                for (int r = 0; r < 4; ++r) red[w - 2][ng][mt][r][lane] = acc[ng][mt][r];
    }
    __syncthreads();
    if (w < 2) {
        #pragma unroll
        for (int ng = 0; ng < 2; ++ng)
            #pragma unroll
            for (int mt = 0; mt < MT; ++mt)
                #pragma unroll
                for (int r = 0; r < 4; ++r) acc[ng][mt][r] += red[w][ng][mt][r][lane];
    }
    __syncthreads();
    if (w == 1) {
        #pragma unroll
        for (int ng = 0; ng < 2; ++ng)
            #pragma unroll
            for (int mt = 0; mt < MT; ++mt)
                #pragma unroll
                for (int r = 0; r < 4; ++r) red[0][ng][mt][r][lane] = acc[ng][mt][r];
    }
    __syncthreads();
    if (w == 0) {
        #pragma unroll
        for (int ng = 0; ng < 2; ++ng) {
            #pragma unroll
            for (int mt = 0; mt < MT; ++mt)
                #pragma unroll
                for (int r = 0; r < 4; ++r) acc[ng][mt][r] += red[0][ng][mt][r][lane];

            const float s = __shfl(acc[ng][4][0], col) + c[SDIM];
            const int b = r0 + ng * 16 + col;
            #pragma unroll
            for (int mt = 0; mt < 4; ++mt) {
                f32x4 cv = *(const f32x4*)(c    + mt * 16 + g4 * 4);
                f32x4 bf = *(const f32x4*)(bfin + mt * 16 + g4 * 4);
                f32x4 ov;
                #pragma unroll
                for (int r = 0; r < 4; ++r) ov[r] = s * (acc[ng][mt][r] + cv[r]) + bf[r];
                *(f32x4*)(out + (size_t)b * SDIM + mt * 16 + g4 * 4) = ov;
            }
        }
    }
}

// ================== fused fallback (round-2 kernel, verbatim) ==================
#define BK     128
#define NCH    (LATENT / BK)

__global__ __launch_bounds__(512, 2) void fused_kernel(
    const float* __restrict__ z,
    const float* __restrict__ wq, const float* __restrict__ bq,
    const float* __restrict__ wk, const float* __restrict__ bk,
    const float* __restrict__ Wf, const float* __restrict__ bfin,
    const int* __restrict__ midx, int F,
    float* __restrict__ out)
{
    __shared__ __align__(16) unsigned char ubuf[2 * 80 * BK * 2];
    __shared__ int   inv[LATENT];
    __shared__ float cvals[68];
    __shared__ float srow[4][16];

    __bf16* Ab = (__bf16*)ubuf;
    float (*red)[MT][4][64] = (float (*)[MT][4][64])ubuf;

    const int tid  = threadIdx.x;
    const int lane = tid & 63;
    const int w    = tid >> 6;
    const int rg   = w & 3;
    const int kh   = w >> 2;
    const int r0   = blockIdx.x * 64 + rg * 16;
    const int col  = lane & 15;
    const int g4   = lane >> 4;

    for (int d = tid; d < LATENT; d += 512) inv[d] = -1;
    __syncthreads();
    for (int f = tid; f < F; f += 512) inv[midx[f]] = f;
    {
        const int o = tid >> 3, fo = tid & 7;
        float p = 0.f;
        for (int f = fo; f < F; f += 8) p += bk[f] * Wf[o * F + f];
        p += __shfl_xor(p, 1); p += __shfl_xor(p, 2); p += __shfl_xor(p, 4);
        if (fo == 0) cvals[o] = p;
    }
    if (w == 0) {
        float q = 0.f;
        for (int f = lane; f < F; f += 64) q += bq[f];
        #pragma unroll
        for (int off = 32; off; off >>= 1) q += __shfl_down(q, off);
        if (lane == 0) cvals[64] = q;
    }
    __syncthreads();

    f32x4 acc[MT] = {};

    auto build = [&](int ch, int b) {
        const int k  = tid & 127;
        const int mb = tid >> 7;
        const int f  = inv[ch * BK + k];
        const float wkf = (f >= 0) ? wk[f] : 0.f;
        const float wqf = (f >= 0) ? wq[f] : 0.f;
        __bf16* dst = Ab + b * 80 * BK;
        #pragma unroll
        for (int i = 0; i < 20; ++i) {
            const int m = mb + 4 * i;
            float x = 0.f;
            if (m < SDIM) { if (f >= 0) x = wkf * Wf[m * F + f]; }
            else if (m == SDIM) x = wqf;
            dst[m * BK + (k ^ ((m & 7) << 3))] = (__bf16)x;
        }
    };

    auto compute = [&](int ch, int b) {
        const float* zp = z + (size_t)(r0 + col) * LATENT + ch * BK + kh * 64 + g4 * 8;
        f32x4 za0 = *(const f32x4*)(zp);
        f32x4 za1 = *(const f32x4*)(zp + 4);
        f32x4 zb0 = *(const f32x4*)(zp + 32);
        f32x4 zb1 = *(const f32x4*)(zp + 36);
        const __bf16* src = Ab + b * 80 * BK;
        const int kl0 = kh * 64 + g4 * 8;
        bf16x8 bv;
        bv[0] = (__bf16)za0[0]; bv[1] = (__bf16)za0[1];
        bv[2] = (__bf16)za0[2]; bv[3] = (__bf16)za0[3];
        bv[4] = (__bf16)za1[0]; bv[5] = (__bf16)za1[1];
        bv[6] = (__bf16)za1[2]; bv[7] = (__bf16)za1[3];
        #pragma unroll
        for (int mt = 0; mt < MT; ++mt) {
            const int m = mt * 16 + col;
            bf16x8 av = *(const bf16x8*)(src + m * BK + (kl0 ^ ((m & 7) << 3)));
            acc[mt] = __builtin_amdgcn_mfma_f32_16x16x32_bf16(av, bv, acc[mt], 0, 0, 0);
        }
        const int kl1 = kl0 + 32;
        bv[0] = (__bf16)zb0[0]; bv[1] = (__bf16)zb0[1];
        bv[2] = (__bf16)zb0[2]; bv[3] = (__bf16)zb0[3];
        bv[4] = (__bf16)zb1[0]; bv[5] = (__bf16)zb1[1];
        bv[6] = (__bf16)zb1[2]; bv[7] = (__bf16)zb1[3];
        #pragma unroll
        for (int mt = 0; mt < MT; ++mt) {
            const int m = mt * 16 + col;
            bf16x8 av = *(const bf16x8*)(src + m * BK + (kl1 ^ ((m & 7) << 3)));
            acc[mt] = __builtin_amdgcn_mfma_f32_16x16x32_bf16(av, bv, acc[mt], 0, 0, 0);
        }
    };

    build(0, 0);
    __syncthreads();
    #pragma unroll 2
    for (int ch = 0; ch < NCH; ++ch) {
        const int b = ch & 1;
        if (ch + 1 < NCH) build(ch + 1, b ^ 1);
        compute(ch, b);
        __syncthreads();
    }

    if (kh == 1) {
        #pragma unroll
        for (int mt = 0; mt < MT; ++mt)
            #pragma unroll
            for (int r = 0; r < 4; ++r) red[rg][mt][r][lane] = acc[mt][r];
    }
    __syncthreads();
    if (kh == 0) {
        #pragma unroll
        for (int mt = 0; mt < MT; ++mt)
            #pragma unroll
            for (int r = 0; r < 4; ++r) acc[mt][r] += red[rg][mt][r][lane];
        if (g4 == 0) srow[rg][col] = acc[4][0];
    }
    __syncthreads();

    if (kh == 0) {
        const float s = srow[rg][col] + cvals[64];
        const int bidx = r0 + col;
        #pragma unroll
        for (int mt = 0; mt < 4; ++mt) {
            f32x4 cv = *(const f32x4*)(cvals + mt * 16 + g4 * 4);
            f32x4 bf = *(const f32x4*)(bfin + mt * 16 + g4 * 4);
            f32x4 ov;
            #pragma unroll
            for (int r = 0; r < 4; ++r) ov[r] = s * (acc[mt][r] + cv[r]) + bf[r];
            *(f32x4*)(out + (size_t)bidx * SDIM + mt * 16 + g4 * 4) = ov;
        }
    }
}

extern "C" void kernel_launch(void* const* d_in, const int* in_sizes, int n_in,
                              void* d_out, int out_size, void* d_ws, size_t ws_size,
                              hipStream_t stream)
{
    const float* z    = (const float*)d_in[0];
    const float* wq   = (const float*)d_in[1];
    const float* bq   = (const float*)d_in[2];
    const float* wk   = (const float*)d_in[3];
    const float* bk   = (const float*)d_in[4];
    const float* Wf   = (const float*)d_in[5];
    const float* bfin = (const float*)d_in[6];
    const int*   midx = (const int*)d_in[7];
    const int F = in_sizes[1];
    float* out = (float*)d_out;

    if (ws_size >= (size_t)WS_NEED) {
        char* ws = (char*)d_ws;
        float*  c     = (float*)ws;                  // 65 floats
        bf16x8* afrag = (bf16x8*)(ws + 4096);        // 640 KB
        prep_c    <<<65,  64,  0, stream>>>(bq, bk, Wf, F, c);
        prep_afrag<<<160, 256, 0, stream>>>(wq, wk, Wf, midx, F, afrag);
        gemm_pipe <<<512, 256, 0, stream>>>(z, afrag, c, bfin, out);
    } else {
        fused_kernel<<<256, 512, 0, stream>>>(z, wq, bq, wk, bk, Wf, bfin, midx, F, out);
    }
}

// Round 10
// 78.060 us; speedup vs baseline: 2.3540x; 1.0258x over previous
//
#include <hip/hip_runtime.h>
#include <hip/hip_bf16.h>

#define LATENT 4096
#define SDIM   64
#define MT     5              // 5 m-tiles of 16 = 80 rows (64 outputs + s_row + pad)
#define CHUNK  128            // floats of K per staged chunk (= 4 k-steps)
#define NCHK   (LATENT / CHUNK)   // 32
#define NBUF   4
#define ROWS   32             // batch rows per block
#define WS_NEED (4096 + 40960 * 16)

typedef __bf16 bf16x8 __attribute__((ext_vector_type(8)));
typedef float  f32x4  __attribute__((ext_vector_type(4)));

#define GLOBAL_AS __attribute__((address_space(1)))
#define LDS_AS    __attribute__((address_space(3)))

__device__ __forceinline__ void load_lds16(const float* g, float* l) {
    __builtin_amdgcn_global_load_lds((const GLOBAL_AS void*)g, (LDS_AS void*)l, 16, 0, 0);
}

#define WAITB(N) do { asm volatile("s_waitcnt vmcnt(" #N ")" ::: "memory"); \
                      __builtin_amdgcn_s_barrier(); } while (0)

// ======================= precompute path (needs d_ws) =======================

__global__ void prep_c(const float* __restrict__ bq, const float* __restrict__ bk,
                       const float* __restrict__ Wf, int F, float* __restrict__ c) {
    int o = blockIdx.x, lane = threadIdx.x;
    float p = 0.f;
    if (o < SDIM) { for (int f = lane; f < F; f += 64) p += bk[f] * Wf[o * F + f]; }
    else          { for (int f = lane; f < F; f += 64) p += bq[f]; }
    for (int off = 32; off; off >>= 1) p += __shfl_down(p, off);
    if (lane == 0) c[o] = p;
}

// bf16 A-fragments, fragment-linear: idx = ((ks*5+mt)*64+lane)
__global__ __launch_bounds__(256) void prep_afrag(
    const float* __restrict__ wq, const float* __restrict__ wk,
    const float* __restrict__ Wf, const int* __restrict__ midx,
    int F, bf16x8* __restrict__ afrag)
{
    __shared__ int inv[LATENT];
    const int t = threadIdx.x;
    #pragma unroll
    for (int d = t; d < LATENT; d += 256) inv[d] = -1;
    __syncthreads();
    for (int f = t; f < F; f += 256) inv[midx[f]] = f;
    __syncthreads();

    const int g = blockIdx.x * 256 + t;          // 0 .. 40959
    const int lane = g & 63;
    const int mt = (g >> 6) % 5;
    const int ks = g / 320;                      // 0 .. 127
    const int m = mt * 16 + (lane & 15);
    const int kbase = ks * 32 + (lane >> 4) * 8;
    bf16x8 v;
    #pragma unroll
    for (int j = 0; j < 8; ++j) {
        int f = inv[kbase + j];
        float x = 0.f;
        if (f >= 0) {
            if (m < SDIM) x = wk[f] * Wf[m * F + f];
            else if (m == SDIM) x = wq[f];
        }
        v[j] = (__bf16)x;
    }
    afrag[g] = v;
}

struct AF { bf16x8 a0, a1, a2, a3, a4; };

// main: D[80 x 16384] = A[80 x 4096] * z^T, counted-vmcnt DEEP ring pipeline.
// 512 blocks x 256 thr (4 waves); 32 rows/block; wave w = k-step w of each chunk.
// Distance-2 issue: at half-iter h issue (loadA(h+2), stage(h+2)), WAIT vmcnt(18)
// -> every load has 2 full half-iterations in flight before forced retire.
__global__ __launch_bounds__(256, 2) void gemm_pipe(
    const float* __restrict__ z, const bf16x8* __restrict__ afrag,
    const float* __restrict__ c, const float* __restrict__ bfin,
    float* __restrict__ out)
{
    __shared__ __align__(16) float zbuf[NBUF][ROWS][CHUNK];   // 64 KB
    float (*red)[2][MT][4][64] = (float (*)[2][MT][4][64])zbuf;  // [grp][ng][mt][r][lane]

    const int tid  = threadIdx.x;
    const int lane = tid & 63;
    const int w    = tid >> 6;     // 0..3 = k-step within chunk
    const int col  = lane & 15;
    const int g4   = lane >> 4;
    const int r0   = blockIdx.x * ROWS;
    const int ra   = 8 * w;        // this wave stages LDS rows ra..ra+7

    // global sources for the 4 staging instrs; column pre-swizzled so that
    // LDS float pos p (linear dest) holds z col (p ^ ((ldsrow&7)<<2)).
    const int half  = lane >> 5;          // 0..1 (row within a 2-row pair)
    const int cbase = (lane & 31) * 4;    // 16B slot within row
    const float* zsrc[4];
    #pragma unroll
    for (int j = 0; j < 4; ++j) {
        const int lrow = ra + 2 * j + half;               // LDS row 0..31
        zsrc[j] = z + (size_t)(r0 + lrow) * LATENT + (cbase ^ ((lrow & 7) << 2));
    }

    f32x4 acc[2][MT] = {};

    auto stage = [&](int cN) {   // 4 VMEM ops
        float* d = &zbuf[cN & 3][ra][0];
        load_lds16(zsrc[0] + cN * CHUNK, d);
        load_lds16(zsrc[1] + cN * CHUNK, d + 256);
        load_lds16(zsrc[2] + cN * CHUNK, d + 512);
        load_lds16(zsrc[3] + cN * CHUNK, d + 768);
    };
    auto loadA = [&](int cN, AF& Fr) {   // 5 VMEM ops
        const bf16x8* p = afrag + (size_t)((cN * 4 + w) * MT) * 64 + lane;
        Fr.a0 = p[0]; Fr.a1 = p[64]; Fr.a2 = p[128]; Fr.a3 = p[192]; Fr.a4 = p[256];
    };
    auto consume = [&](int cN, const AF& Fr) {
        const int q = cN & 3;
        const int base = w * 32 + g4 * 8;          // multiple of 8
        const int b0 = base ^ ((col & 7) << 2);    // 16B-aligned (b0 % 4 == 0)
        #pragma unroll
        for (int ng = 0; ng < 2; ++ng) {
            const float* pr = &zbuf[q][ng * 16 + col][0];
            f32x4 a = *(const f32x4*)(pr + b0);
            f32x4 b = *(const f32x4*)(pr + (b0 ^ 4));
            bf16x8 bv;
            bv[0] = (__bf16)a[0]; bv[1] = (__bf16)a[1];
            bv[2] = (__bf16)a[2]; bv[3] = (__bf16)a[3];
            bv[4] = (__bf16)b[0]; bv[5] = (__bf16)b[1];
            bv[6] = (__bf16)b[2]; bv[7] = (__bf16)b[3];
            acc[ng][0] = __builtin_amdgcn_mfma_f32_16x16x32_bf16(Fr.a0, bv, acc[ng][0], 0, 0, 0);
            acc[ng][1] = __builtin_amdgcn_mfma_f32_16x16x32_bf16(Fr.a1, bv, acc[ng][1], 0, 0, 0);
            acc[ng][2] = __builtin_amdgcn_mfma_f32_16x16x32_bf16(Fr.a2, bv, acc[ng][2], 0, 0, 0);
            acc[ng][3] = __builtin_amdgcn_mfma_f32_16x16x32_bf16(Fr.a3, bv, acc[ng][3], 0, 0, 0);
            acc[ng][4] = __builtin_amdgcn_mfma_f32_16x16x32_bf16(Fr.a4, bv, acc[ng][4], 0, 0, 0);
        }
    };

    AF f_a, f_b, f_c;
    // prologue: sets "-2" = (loadA0,stage0), "-1" = (loadA1,stage1) -> 18 outstanding
    loadA(0, f_a); stage(0);
    loadA(1, f_b); stage(1);

    // steady state, period-3 register rotation; each body: issue set h (9 ops),
    // WAIT vmcnt(18) (leaves sets {h-1,h}), retire set h-2, consume(h).
    for (int hb = 0; hb < NCHK - 2; hb += 3) {
        loadA(hb + 2, f_c); stage(hb + 2);
        WAITB(18); consume(hb,     f_a);
        loadA(hb + 3, f_a); stage(hb + 3);
        WAITB(18); consume(hb + 1, f_b);
        loadA(hb + 4, f_b); stage(hb + 4);
        WAITB(18); consume(hb + 2, f_c);
    }
    // tail: outstanding = sets {28,29}; retire 28 then 29
    WAITB(9); consume(30, f_a);
    WAITB(0); consume(31, f_b);

    // ---- reduce the 4 k-phase partials (zbuf reused; barrier protects) ----
    __syncthreads();
    if (w >= 2) {
        #pragma unroll
        for (int ng = 0; ng < 2; ++ng)
            #pragma unroll
            for (int mt = 0; mt < MT; ++mt)
                #pragma unroll
                for (int r = 0; r < 4; ++r) red[w - 2][ng][mt][r][lane] = acc[ng][mt][r];
    }
    __syncthreads();
    if (w < 2) {
        #pragma unroll
        for (int ng = 0; ng < 2; ++ng)
            #pragma unroll
            for (int mt = 0; mt < MT; ++mt)
                #pragma unroll
                for (int r = 0; r < 4; ++r) acc[ng][mt][r] += red[w][ng][mt][r][lane];
    }
    __syncthreads();
    if (w == 1) {
        #pragma unroll
        for (int ng = 0; ng < 2; ++ng)
            #pragma unroll
            for (int mt = 0; mt < MT; ++mt)
                #pragma unroll
                for (int r = 0; r < 4; ++r) red[0][ng][mt][r][lane] = acc[ng][mt][r];
    }
    __syncthreads();
    if (w == 0) {
        #pragma unroll
        for (int ng = 0; ng < 2; ++ng) {
            #pragma unroll
            for (int mt = 0; mt < MT; ++mt)
                #pragma unroll
                for (int r = 0; r < 4; ++r) acc[ng][mt][r] += red[0][ng][mt][r][lane];

            const float s = __shfl(acc[ng][4][0], col) + c[SDIM];
            const int b = r0 + ng * 16 + col;
            #pragma unroll
            for (int mt = 0; mt < 4; ++mt) {
                f32x4 cv = *(const f32x4*)(c    + mt * 16 + g4 * 4);
                f32x4 bf = *(const f32x4*)(bfin + mt * 16 + g4 * 4);
                f32x4 ov;
                #pragma unroll
                for (int r = 0; r < 4; ++r) ov[r] = s * (acc[ng][mt][r] + cv[r]) + bf[r];
                *(f32x4*)(out + (size_t)b * SDIM + mt * 16 + g4 * 4) = ov;
            }
        }
    }
}

// ================== fused fallback (round-2 kernel, verbatim) ==================
#define BK     128
#define NCH    (LATENT / BK)

__global__ __launch_bounds__(512, 2) void fused_kernel(
    const float* __restrict__ z,
    const float* __restrict__ wq, const float* __restrict__ bq,
    const float* __restrict__ wk, const float* __restrict__ bk,
    const float* __restrict__ Wf, const float* __restrict__ bfin,
    const int* __restrict__ midx, int F,
    float* __restrict__ out)
{
    __shared__ __align__(16) unsigned char ubuf[2 * 80 * BK * 2];
    __shared__ int   inv[LATENT];
    __shared__ float cvals[68];
    __shared__ float srow[4][16];

    __bf16* Ab = (__bf16*)ubuf;
    float (*red)[MT][4][64] = (float (*)[MT][4][64])ubuf;

    const int tid  = threadIdx.x;
    const int lane = tid & 63;
    const int w    = tid >> 6;
    const int rg   = w & 3;
    const int kh   = w >> 2;
    const int r0   = blockIdx.x * 64 + rg * 16;
    const int col  = lane & 15;
    const int g4   = lane >> 4;

    for (int d = tid; d < LATENT; d += 512) inv[d] = -1;
    __syncthreads();
    for (int f = tid; f < F; f += 512) inv[midx[f]] = f;
    {
        const int o = tid >> 3, fo = tid & 7;
        float p = 0.f;
        for (int f = fo; f < F; f += 8) p += bk[f] * Wf[o * F + f];
        p += __shfl_xor(p, 1); p += __shfl_xor(p, 2); p += __shfl_xor(p, 4);
        if (fo == 0) cvals[o] = p;
    }
    if (w == 0) {
        float q = 0.f;
        for (int f = lane; f < F; f += 64) q += bq[f];
        #pragma unroll
        for (int off = 32; off; off >>= 1) q += __shfl_down(q, off);
        if (lane == 0) cvals[64] = q;
    }
    __syncthreads();

    f32x4 acc[MT] = {};

    auto build = [&](int ch, int b) {
        const int k  = tid & 127;
        const int mb = tid >> 7;
        const int f  = inv[ch * BK + k];
        const float wkf = (f >= 0) ? wk[f] : 0.f;
        const float wqf = (f >= 0) ? wq[f] : 0.f;
        __bf16* dst = Ab + b * 80 * BK;
        #pragma unroll
        for (int i = 0; i < 20; ++i) {
            const int m = mb + 4 * i;
            float x = 0.f;
            if (m < SDIM) { if (f >= 0) x = wkf * Wf[m * F + f]; }
            else if (m == SDIM) x = wqf;
            dst[m * BK + (k ^ ((m & 7) << 3))] = (__bf16)x;
        }
    };

    auto compute = [&](int ch, int b) {
        const float* zp = z + (size_t)(r0 + col) * LATENT + ch * BK + kh * 64 + g4 * 8;
        f32x4 za0 = *(const f32x4*)(zp);
        f32x4 za1 = *(const f32x4*)(zp + 4);
        f32x4 zb0 = *(const f32x4*)(zp + 32);
        f32x4 zb1 = *(const f32x4*)(zp + 36);
        const __bf16* src = Ab + b * 80 * BK;
        const int kl0 = kh * 64 + g4 * 8;
        bf16x8 bv;
        bv[0] = (__bf16)za0[0]; bv[1] = (__bf16)za0[1];
        bv[2] = (__bf16)za0[2]; bv[3] = (__bf16)za0[3];
        bv[4] = (__bf16)za1[0]; bv[5] = (__bf16)za1[1];
        bv[6] = (__bf16)za1[2]; bv[7] = (__bf16)za1[3];
        #pragma unroll
        for (int mt = 0; mt < MT; ++mt) {
            const int m = mt * 16 + col;
            bf16x8 av = *(const bf16x8*)(src + m * BK + (kl0 ^ ((m & 7) << 3)));
            acc[mt] = __builtin_amdgcn_mfma_f32_16x16x32_bf16(av, bv, acc[mt], 0, 0, 0);
        }
        const int kl1 = kl0 + 32;
        bv[0] = (__bf16)zb0[0]; bv[1] = (__bf16)zb0[1];
        bv[2] = (__bf16)zb0[2]; bv[3] = (__bf16)zb0[3];
        bv[4] = (__bf16)zb1[0]; bv[5] = (__bf16)zb1[1];
        bv[6] = (__bf16)zb1[2]; bv[7] = (__bf16)zb1[3];
        #pragma unroll
        for (int mt = 0; mt < MT; ++mt) {
            const int m = mt * 16 + col;
            bf16x8 av = *(const bf16x8*)(src + m * BK + (kl1 ^ ((m & 7) << 3)));
            acc[mt] = __builtin_amdgcn_mfma_f32_16x16x32_bf16(av, bv, acc[mt], 0, 0, 0);
        }
    };

    build(0, 0);
    __syncthreads();
    #pragma unroll 2
    for (int ch = 0; ch < NCH; ++ch) {
        const int b = ch & 1;
        if (ch + 1 < NCH) build(ch + 1, b ^ 1);
        compute(ch, b);
        __syncthreads();
    }

    if (kh == 1) {
        #pragma unroll
        for (int mt = 0; mt < MT; ++mt)
            #pragma unroll
            for (int r = 0; r < 4; ++r) red[rg][mt][r][lane] = acc[mt][r];
    }
    __syncthreads();
    if (kh == 0) {
        #pragma unroll
        for (int mt = 0; mt < MT; ++mt)
            #pragma unroll
            for (int r = 0; r < 4; ++r) acc[mt][r] += red[rg][mt][r][lane];
        if (g4 == 0) srow[rg][col] = acc[4][0];
    }
    __syncthreads();

    if (kh == 0) {
        const float s = srow[rg][col] + cvals[64];
        const int bidx = r0 + col;
        #pragma unroll
        for (int mt = 0; mt < 4; ++mt) {
            f32x4 cv = *(const f32x4*)(cvals + mt * 16 + g4 * 4);
            f32x4 bf = *(const f32x4*)(bfin + mt * 16 + g4 * 4);
            f32x4 ov;
            #pragma unroll
            for (int r = 0; r < 4; ++r) ov[r] = s * (acc[mt][r] + cv[r]) + bf[r];
            *(f32x4*)(out + (size_t)bidx * SDIM + mt * 16 + g4 * 4) = ov;
        }
    }
}

extern "C" void kernel_launch(void* const* d_in, const int* in_sizes, int n_in,
                              void* d_out, int out_size, void* d_ws, size_t ws_size,
                              hipStream_t stream)
{
    const float* z    = (const float*)d_in[0];
    const float* wq   = (const float*)d_in[1];
    const float* bq   = (const float*)d_in[2];
    const float* wk   = (const float*)d_in[3];
    const float* bk   = (const float*)d_in[4];
    const float* Wf   = (const float*)d_in[5];
    const float* bfin = (const float*)d_in[6];
    const int*   midx = (const int*)d_in[7];
    const int F = in_sizes[1];
    float* out = (float*)d_out;

    if (ws_size >= (size_t)WS_NEED) {
        char* ws = (char*)d_ws;
        float*  c     = (float*)ws;                  // 65 floats
        bf16x8* afrag = (bf16x8*)(ws + 4096);        // 640 KB
        prep_c    <<<65,  64,  0, stream>>>(bq, bk, Wf, F, c);
        prep_afrag<<<160, 256, 0, stream>>>(wq, wk, Wf, midx, F, afrag);
        gemm_pipe <<<512, 256, 0, stream>>>(z, afrag, c, bfin, out);
    } else {
        fused_kernel<<<256, 512, 0, stream>>>(z, wq, bq, wk, bk, Wf, bfin, midx, F, out);
    }
}